// Round 9
// baseline (4871.650 us; speedup 1.0000x reference)
//
#include <hip/hip_runtime.h>
#include <hip/hip_bf16.h>
#include <stdint.h>

typedef __hip_bfloat16 hbf;
typedef unsigned short u16;
typedef __attribute__((ext_vector_type(8))) short bfrag;   // 8 bf16 = 4 VGPRs
typedef __attribute__((ext_vector_type(4))) float f4;      // 16x16 accumulator

#define NP0 50000
#define NP1 20000
#define NP2 8000
#define NP3 3200
#define NP4 1300

static inline int cdiv(int a, int b) { return (a + b - 1) / b; }

static __device__ __forceinline__ float u2f(u16 u) { return __uint_as_float(((unsigned)u) << 16); }
static __device__ __forceinline__ u16 f2u(float f) {
  hbf h = __float2bfloat16(f);
  u16 r; __builtin_memcpy(&r, &h, 2); return r;
}
static __device__ __forceinline__ float pload(const void* P, int isbf, size_t i) {
  return isbf ? u2f(((const u16*)P)[i]) : ((const float*)P)[i];
}

// Weight fragments: hi/lo split planes. On a bf16 wire the lo plane is exactly
// zero (bf16->f32->bf16 round-trips exactly), so the Ahi*Blo MFMA pass is
// skipped at runtime with bit-identical results.

struct PrepD {
  long cpre;   // chunk prefix (global chunk id where this layer starts)
  long src;    // param element offset
  long dst;    // fragment element offset (hi plane)
  int K, CI, CO, CB32, NT16, pad;
};

// ---- dtype sniffer: bf16 wire (flag=1) vs fp32 wire (flag=0) ----
__global__ void k_sniff(const void* __restrict__ xraw, int* __restrict__ flagp) {
  __shared__ float smax[256];
  const u16* u = (const u16*)xraw;
  float m = 0.f;
  for (int i = threadIdx.x; i < 2048; i += 256) {
    float v = u2f(u[2 * i]);
    if (isnan(v) || isinf(v)) m = 1e30f; else m = fmaxf(m, fabsf(v));
  }
  smax[threadIdx.x] = m;
  __syncthreads();
  for (int s = 128; s > 0; s >>= 1) {
    if (threadIdx.x < s) smax[threadIdx.x] = fmaxf(smax[threadIdx.x], smax[threadIdx.x + s]);
    __syncthreads();
  }
  if (threadIdx.x == 0) *flagp = (smax[0] < 1e4f) ? 1 : 0;
}

// ---- unified one-shot weight prep over all layers (table-driven) ----
__global__ __launch_bounds__(256) void k_prep_all(
    const void* __restrict__ P, const int* __restrict__ flagp, u16* __restrict__ W,
    const PrepD* __restrict__ T, int NL, long totalC, long totalE)
{
  int f = *flagp;
  int L = 0;
  for (long c = (long)blockIdx.x * 256 + threadIdx.x; c < totalC; c += (long)gridDim.x * 256) {
    while (L + 1 < NL && c >= T[L + 1].cpre) ++L;
    PrepD d = T[L];
    long lc = c - d.cpre;
    int lane = (int)(lc & 63); long t = lc >> 6;
    int nt = (int)(t % d.NT16); t /= d.NT16;
    int cb = (int)(t % d.CB32); int k = (int)(t / d.CB32);
    int co = nt * 16 + (lane & 15);
    int cib = cb * 32 + (lane >> 4) * 8;
    u16 hi[8], lo[8];
#pragma unroll
    for (int j = 0; j < 8; ++j) {
      int ci = cib + j; float v = 0.f;
      if (ci < d.CI && co < d.CO) v = pload(P, f, d.src + ((size_t)k * d.CI + ci) * d.CO + co);
      u16 h = f2u(v);
      hi[j] = h;
      lo[j] = f2u(v - u2f(h));
    }
    *(bfrag*)(W + d.dst + lc * 8) = *(const bfrag*)hi;
    *(bfrag*)(W + totalE + d.dst + lc * 8) = *(const bfrag*)lo;
  }
}

// ---- per-layer weight prep (fallback when workspace too small) ----
__global__ __launch_bounds__(256) void k_prep_frag(
    const void* __restrict__ P, const int* __restrict__ flagp, u16* __restrict__ W,
    long src, long halfel, int K, int CI, int CO, int CB32, int NT16)
{
  int f = *flagp;
  long total = (long)K * CB32 * NT16 * 64;
  for (long c = (long)blockIdx.x * 256 + threadIdx.x; c < total; c += (long)gridDim.x * 256) {
    int lane = (int)(c & 63); long t = c >> 6;
    int nt = (int)(t % NT16); t /= NT16;
    int cb = (int)(t % CB32); int k = (int)(t / CB32);
    int co = nt * 16 + (lane & 15);
    int cib = cb * 32 + (lane >> 4) * 8;
    u16 hi[8], lo[8];
#pragma unroll
    for (int j = 0; j < 8; ++j) {
      int ci = cib + j; float v = 0.f;
      if (ci < CI && co < CO) v = pload(P, f, src + ((size_t)k * CI + ci) * CO + co);
      u16 h = f2u(v);
      hi[j] = h;
      lo[j] = f2u(v - u2f(h));
    }
    *(bfrag*)(W + c * 8) = *(const bfrag*)hi;
    *(bfrag*)(W + halfel + c * 8) = *(const bfrag*)lo;
  }
}

// ---- bias prep ----
__global__ void k_prep_bias(const void* __restrict__ P, const int* __restrict__ flagp,
                            float* __restrict__ B, long src, int n)
{
  int f = *flagp;
  int i = blockIdx.x * 256 + threadIdx.x;
  if (i < n) B[i] = pload(P, f, src + i);
}

// ---- pad input x [N,4] -> fp32 [N,32] ----
__global__ void k_pad(const void* __restrict__ xraw, const int* __restrict__ flagp,
                      float* __restrict__ Xp, int N)
{
  int f = *flagp; int total = N * 32;
  for (int i = blockIdx.x * 256 + threadIdx.x; i < total; i += gridDim.x * 256) {
    int n = i >> 5, cc = i & 31;
    Xp[i] = (cc < 4) ? pload(xraw, f, (size_t)n * 4 + cc) : 0.f;
  }
}

// ---- split-bf16 MFMA gather-GEMM (16x16x32), reduction-split over gridDim.z ----
// k-outer / cb-inner with per-k hoisted indices; inner iterations independent
// (#pragma unroll 2) so two t-steps' gathers stay in flight. Loop variant
// chosen ONCE per block: bf16 wire -> 2 MFMAs/pair; fp32 wire -> 3.
template<int NT>
__global__ __launch_bounds__(256) void k_conv_mfma(
    const float* __restrict__ X, const int* __restrict__ nbr,
    const u16* __restrict__ Wp, long halfel, float* __restrict__ Y,
    const float* __restrict__ bias, int relu, const int* __restrict__ flagp,
    int N, int K, int CB32, int NT16, int CO, int XS, int tlen, int atomic)
{
  const int f = *flagp;
  const int lane = threadIdx.x & 63;
  const int wv = threadIdx.x >> 6;
  const int rowbase = blockIdx.x * 128 + wv * 32;
  const int ntb = blockIdx.y * NT;
  const int ml = lane & 15;
  const int quad = lane >> 4;
  const int ktot = K * CB32;
  const int t0 = blockIdx.z * tlen;
  const int t1 = (t0 + tlen < ktot) ? (t0 + tlen) : ktot;
  if (t0 >= t1) return;

  f4 acc[2][NT];
#pragma unroll
  for (int i = 0; i < 2; ++i)
#pragma unroll
    for (int j = 0; j < NT; ++j) acc[i][j] = (f4)(0.f);

  const int kbeg = t0 / CB32;
  const int kend = (t1 - 1) / CB32;
  const int cb0 = t0 - kbeg * CB32;
  const int cbE = (t1 - 1) - kend * CB32 + 1;

  if (f) {
    // bf16 wire: weight lo-plane exactly zero -> 2 MFMAs per pair
    for (int k = kbeg; k <= kend; ++k) {
      int cs = (k == kbeg) ? cb0 : 0;
      int ce = (k == kend) ? cbE : CB32;
      int idx[2];
#pragma unroll
      for (int mt = 0; mt < 2; ++mt) {
        int r = rowbase + mt * 16 + ml;
        idx[mt] = (r < N) ? (nbr ? nbr[(size_t)r * K + k] : r) : 0;
      }
#pragma unroll 2
      for (int cb = cs; cb < ce; ++cb) {
        const u16* WH = Wp + (size_t)(k * CB32 + cb) * NT16 * 512;
        bfrag bh[NT];
#pragma unroll
        for (int nt = 0; nt < NT; ++nt) {
          size_t o = ((size_t)(ntb + nt) * 64 + lane) * 8;
          bh[nt] = *(const bfrag*)(WH + o);
        }
        bfrag ahi[2], alo[2];
#pragma unroll
        for (int mt = 0; mt < 2; ++mt) {
          const float* ap = X + (size_t)idx[mt] * XS + cb * 32 + quad * 8;
          float4 q0 = *(const float4*)ap;
          float4 q1 = *(const float4*)(ap + 4);
          float av[8] = {q0.x, q0.y, q0.z, q0.w, q1.x, q1.y, q1.z, q1.w};
          u16 hi8[8], lo8[8];
#pragma unroll
          for (int j = 0; j < 8; ++j) {
            u16 hh = f2u(av[j]);
            hi8[j] = hh;
            lo8[j] = f2u(av[j] - u2f(hh));
          }
          __builtin_memcpy(&ahi[mt], hi8, 16);
          __builtin_memcpy(&alo[mt], lo8, 16);
        }
#pragma unroll
        for (int mt = 0; mt < 2; ++mt)
#pragma unroll
          for (int nt = 0; nt < NT; ++nt) {
            acc[mt][nt] = __builtin_amdgcn_mfma_f32_16x16x32_bf16(alo[mt], bh[nt], acc[mt][nt], 0, 0, 0);
            acc[mt][nt] = __builtin_amdgcn_mfma_f32_16x16x32_bf16(ahi[mt], bh[nt], acc[mt][nt], 0, 0, 0);
          }
      }
    }
  } else {
    // fp32 wire: full 3-MFMA split path
    for (int k = kbeg; k <= kend; ++k) {
      int cs = (k == kbeg) ? cb0 : 0;
      int ce = (k == kend) ? cbE : CB32;
      int idx[2];
#pragma unroll
      for (int mt = 0; mt < 2; ++mt) {
        int r = rowbase + mt * 16 + ml;
        idx[mt] = (r < N) ? (nbr ? nbr[(size_t)r * K + k] : r) : 0;
      }
#pragma unroll 2
      for (int cb = cs; cb < ce; ++cb) {
        const u16* WH = Wp + (size_t)(k * CB32 + cb) * NT16 * 512;
        const u16* WL = WH + halfel;
        bfrag bh[NT], bl[NT];
#pragma unroll
        for (int nt = 0; nt < NT; ++nt) {
          size_t o = ((size_t)(ntb + nt) * 64 + lane) * 8;
          bh[nt] = *(const bfrag*)(WH + o);
          bl[nt] = *(const bfrag*)(WL + o);
        }
        bfrag ahi[2], alo[2];
#pragma unroll
        for (int mt = 0; mt < 2; ++mt) {
          const float* ap = X + (size_t)idx[mt] * XS + cb * 32 + quad * 8;
          float4 q0 = *(const float4*)ap;
          float4 q1 = *(const float4*)(ap + 4);
          float av[8] = {q0.x, q0.y, q0.z, q0.w, q1.x, q1.y, q1.z, q1.w};
          u16 hi8[8], lo8[8];
#pragma unroll
          for (int j = 0; j < 8; ++j) {
            u16 hh = f2u(av[j]);
            hi8[j] = hh;
            lo8[j] = f2u(av[j] - u2f(hh));
          }
          __builtin_memcpy(&ahi[mt], hi8, 16);
          __builtin_memcpy(&alo[mt], lo8, 16);
        }
#pragma unroll
        for (int mt = 0; mt < 2; ++mt)
#pragma unroll
          for (int nt = 0; nt < NT; ++nt) {
            acc[mt][nt] = __builtin_amdgcn_mfma_f32_16x16x32_bf16(alo[mt], bh[nt], acc[mt][nt], 0, 0, 0);
            acc[mt][nt] = __builtin_amdgcn_mfma_f32_16x16x32_bf16(ahi[mt], bl[nt], acc[mt][nt], 0, 0, 0);
            acc[mt][nt] = __builtin_amdgcn_mfma_f32_16x16x32_bf16(ahi[mt], bh[nt], acc[mt][nt], 0, 0, 0);
          }
      }
    }
  }

  // epilogue: C/D layout col=lane&15, row=quad*4+reg (m89/m91 verified)
#pragma unroll
  for (int mt = 0; mt < 2; ++mt) {
#pragma unroll
    for (int nt = 0; nt < NT; ++nt) {
      int col = (ntb + nt) * 16 + ml;
      if (col >= CO) continue;
      float bvv = bias ? bias[col] : 0.f;
#pragma unroll
      for (int reg = 0; reg < 4; ++reg) {
        int row = rowbase + mt * 16 + quad * 4 + reg;
        if (row < N) {
          if (atomic) {
            atomicAdd(&Y[(size_t)row * CO + col], acc[mt][nt][reg]);
          } else {
            float v = acc[mt][nt][reg] + bvv;
            if (relu) v = fmaxf(v, 0.f);
            Y[(size_t)row * CO + col] = v;
          }
        }
      }
    }
  }
}

// ---- finalize after atomic-split conv: Y = relu(Y + bias) ----
__global__ void k_bias_relu(float* __restrict__ Y, const float* __restrict__ bias,
                            int relu, int total, int CO)
{
  int stride = gridDim.x * 256;
  for (int i = blockIdx.x * 256 + threadIdx.x; i < total; i += stride) {
    int c = i % CO;
    float v = Y[i] + (bias ? bias[c] : 0.f);
    if (relu) v = fmaxf(v, 0.f);
    Y[i] = v;
  }
}

static void launch_conv(hipStream_t s, int bx, const float* X, const int* nbr,
                        const u16* W, long halfel, float* Y, const float* bias, int relu,
                        const int* flagp, int N, int K, int CB32, int NT16, int CO, int XS)
{
  int NT = (NT16 % 6 == 0) ? 6 : ((NT16 % 4 == 0) ? 4 : 2);
  int ny = NT16 / NT;
  int ktot = K * CB32;
  long blocks = (long)bx * ny;
  int ZS = 1;
  if (ktot > 1) {
    ZS = (int)((2048 + blocks - 1) / blocks);
    if (ZS > ktot) ZS = ktot;
    if (ZS < 1) ZS = 1;
  }
  int tlen = cdiv(ktot, ZS);
  ZS = cdiv(ktot, tlen);
  int atomic = (ZS > 1) ? 1 : 0;
  if (atomic) hipMemsetAsync(Y, 0, (size_t)N * CO * 4, s);
  dim3 g(bx, ny, ZS);
  if (NT == 6)      k_conv_mfma<6><<<g, 256, 0, s>>>(X, nbr, W, halfel, Y, bias, relu, flagp, N, K, CB32, NT16, CO, XS, tlen, atomic);
  else if (NT == 4) k_conv_mfma<4><<<g, 256, 0, s>>>(X, nbr, W, halfel, Y, bias, relu, flagp, N, K, CB32, NT16, CO, XS, tlen, atomic);
  else              k_conv_mfma<2><<<g, 256, 0, s>>>(X, nbr, W, halfel, Y, bias, relu, flagp, N, K, CB32, NT16, CO, XS, tlen, atomic);
  if (atomic && (bias || relu)) {
    int total = N * CO;
    int nb = cdiv(total, 1024); if (nb > 1024) nb = 1024; if (nb < 1) nb = 1;
    k_bias_relu<<<nb, 256, 0, s>>>(Y, bias, relu, total, CO);
  }
}

// ---- transposed ks=2 conv ----
__global__ __launch_bounds__(256) void k_deconv(
    const float* __restrict__ X, const int* __restrict__ par, const int* __restrict__ off,
    const void* __restrict__ P, long wofs, const int* __restrict__ flagp,
    float* __restrict__ Y, int N, int CI, int CO)
{
  int f = *flagp;
  int lane = threadIdx.x & 63, wv = threadIdx.x >> 6;
  int n = blockIdx.y * 4 + wv; if (n >= N) return;
  int co = blockIdx.x * 64 + lane; if (co >= CO) return;
  const float* xr = X + (size_t)par[n] * CI;
  size_t wbase = wofs + (size_t)off[n] * CI * CO + co;
  float acc = 0.f;
  for (int ci = 0; ci < CI; ci += 4) {   // CI is a multiple of 4 throughout
    float4 xv = *(const float4*)(xr + ci);
    acc += xv.x * pload(P, f, wbase + (size_t)ci * CO);
    acc += xv.y * pload(P, f, wbase + (size_t)(ci + 1) * CO);
    acc += xv.z * pload(P, f, wbase + (size_t)(ci + 2) * CO);
    acc += xv.w * pload(P, f, wbase + (size_t)(ci + 3) * CO);
  }
  Y[(size_t)n * CO + co] = acc;
}

// ---- BN (fp32, float4-vectorized; gridDim multiple of 3 so each thread's
//      4 channels are loop-invariant for every C in the net) ----
__global__ __launch_bounds__(256) void k_bn_stats(
    const float* __restrict__ X, float* __restrict__ st, int total, int C)
{
  __shared__ float ssum[384], ssq[384];
  for (int c = threadIdx.x; c < C; c += 256) { ssum[c] = 0.f; ssq[c] = 0.f; }
  __syncthreads();
  int gid = blockIdx.x * 256 + threadIdx.x;
  int total4 = total >> 2;
  int stride = gridDim.x * 256;
  int c0 = (gid * 4) % C;   // invariant: (stride*4) % C == 0 (grid mult of 3)
  float s0 = 0.f, s1 = 0.f, s2 = 0.f, s3 = 0.f;
  float q0 = 0.f, q1 = 0.f, q2 = 0.f, q3 = 0.f;
  for (int i = gid; i < total4; i += stride) {
    float4 v = ((const float4*)X)[i];
    s0 += v.x; q0 += v.x * v.x;
    s1 += v.y; q1 += v.y * v.y;
    s2 += v.z; q2 += v.z * v.z;
    s3 += v.w; q3 += v.w * v.w;
  }
  atomicAdd(&ssum[c0], s0);     atomicAdd(&ssq[c0], q0);
  atomicAdd(&ssum[c0 + 1], s1); atomicAdd(&ssq[c0 + 1], q1);
  atomicAdd(&ssum[c0 + 2], s2); atomicAdd(&ssq[c0 + 2], q2);
  atomicAdd(&ssum[c0 + 3], s3); atomicAdd(&ssq[c0 + 3], q3);
  __syncthreads();
  for (int c = threadIdx.x; c < C; c += 256) {
    atomicAdd(&st[c], ssum[c]); atomicAdd(&st[384 + c], ssq[c]);
  }
}

__global__ __launch_bounds__(256) void k_bn_apply(
    const float* __restrict__ X, const float* __restrict__ st, const float* __restrict__ add,
    float* __restrict__ Y, int relu, int total, int C, float invN)
{
  __shared__ float mean[384], rsig[384];
  for (int c = threadIdx.x; c < C; c += 256) {
    float mm = st[c] * invN;
    float vv = st[384 + c] * invN - mm * mm;
    mean[c] = mm; rsig[c] = rsqrtf(vv + 1e-5f);
  }
  __syncthreads();
  int gid = blockIdx.x * 256 + threadIdx.x;
  int total4 = total >> 2;
  int stride = gridDim.x * 256;
  int c0 = (gid * 4) % C;   // invariant across iterations (grid mult of 3)
  float m0 = mean[c0], m1 = mean[c0 + 1], m2 = mean[c0 + 2], m3 = mean[c0 + 3];
  float r0 = rsig[c0], r1 = rsig[c0 + 1], r2 = rsig[c0 + 2], r3 = rsig[c0 + 3];
  for (int i = gid; i < total4; i += stride) {
    float4 v = ((const float4*)X)[i];
    v.x = (v.x - m0) * r0; v.y = (v.y - m1) * r1;
    v.z = (v.z - m2) * r2; v.w = (v.w - m3) * r3;
    if (add) {
      float4 a = ((const float4*)add)[i];
      v.x += a.x; v.y += a.y; v.z += a.z; v.w += a.w;
    }
    if (relu) {
      v.x = fmaxf(v.x, 0.f); v.y = fmaxf(v.y, 0.f);
      v.z = fmaxf(v.z, 0.f); v.w = fmaxf(v.w, 0.f);
    }
    ((float4*)Y)[i] = v;
  }
}

__global__ void k_copycols(const float* __restrict__ S, float* __restrict__ D,
                           int N, int Cs, int Cd, int off)
{
  int csq = Cs >> 2;
  int total4 = N * csq;
  int stride = gridDim.x * 256;
  for (int i = blockIdx.x * 256 + threadIdx.x; i < total4; i += stride) {
    int n = i / csq, cc = i - n * csq;
    ((float4*)D)[((size_t)n * Cd + off) / 4 + cc] = ((const float4*)S)[i];
  }
}

__global__ void k_store_dyn(const float* __restrict__ S, void* __restrict__ D,
                            const int* __restrict__ flagp, size_t eofs, int n)
{
  int f = *flagp;
  int n4 = n >> 2;
  int stride = gridDim.x * 256;
  for (int i = blockIdx.x * 256 + threadIdx.x; i < n4; i += stride) {
    float4 v = ((const float4*)S)[i];
    if (f) {
      ushort4 u;
      u.x = f2u(v.x); u.y = f2u(v.y); u.z = f2u(v.z); u.w = f2u(v.w);
      *(ushort4*)((u16*)D + eofs + (size_t)i * 4) = u;
    } else {
      *(float4*)((float*)D + eofs + (size_t)i * 4) = v;
    }
  }
}

// ---- host-side: static table of all prepped weights in execution order ----
static int build_table(PrepD* T, long* totalC, long* totalE) {
  int n = 0; long po = 0, ce = 0, cc = 0;
  auto W = [&](int K, int CI, int CO) {
    int CB = cdiv(CI, 32), NTx = cdiv(CO, 16);
    long ch = (long)K * CB * NTx * 64;
    T[n].cpre = cc; T[n].src = po; T[n].dst = ce;
    T[n].K = K; T[n].CI = CI; T[n].CO = CO; T[n].CB32 = CB; T[n].NT16 = NTx; T[n].pad = 0;
    ++n; cc += ch; ce += ch * 8; po += (long)K * CI * CO;
  };
  auto SKIP = [&](long e) { po += e; };
  W(27, 4, 32); W(27, 32, 32);                                        // stem
  W(8, 32, 32); W(27, 32, 32); W(27, 32, 32); W(27, 32, 32); W(27, 32, 32);           // s1
  W(8, 32, 32); W(27, 32, 64); W(27, 64, 64); W(1, 32, 64); W(27, 64, 64); W(27, 64, 64);   // s2
  W(8, 64, 64); W(27, 64, 128); W(27, 128, 128); W(1, 64, 128); W(27, 128, 128); W(27, 128, 128); // s3
  W(8, 128, 128); W(27, 128, 256); W(27, 256, 256); W(1, 128, 256); W(27, 256, 256); W(27, 256, 256); // s4
  SKIP(8L * 256 * 256);
  W(27, 384, 256); W(27, 256, 256); W(1, 384, 256); W(27, 256, 256); W(27, 256, 256); // up1
  SKIP(8L * 256 * 128);
  W(27, 192, 128); W(27, 128, 128); W(1, 192, 128); W(27, 128, 128); W(27, 128, 128); // up2
  SKIP(8L * 128 * 96);
  W(27, 128, 96); W(27, 96, 96); W(1, 128, 96); W(27, 96, 96); W(27, 96, 96);       // up3
  SKIP(8L * 96 * 96);
  W(27, 128, 96); W(27, 96, 96); W(1, 128, 96); W(27, 96, 96); W(27, 96, 96);       // up4
  W(1, 96, 19); SKIP(19); W(1, 96, 96); SKIP(96); W(1, 96, 128); SKIP(128);         // head
  *totalC = cc; *totalE = ce;
  return n;
}

// ---------------- host orchestration ----------------

extern "C" void kernel_launch(void* const* d_in, const int* in_sizes, int n_in,
                              void* d_out, int out_size, void* d_ws, size_t ws_size,
                              hipStream_t stream)
{
  const void* xraw = d_in[0];
  const int* nbr0 = (const int*)d_in[1];
  const int* nbr1 = (const int*)d_in[2];
  const int* nbr2 = (const int*)d_in[3];
  const int* nbr3 = (const int*)d_in[4];
  const int* nbr4 = (const int*)d_in[5];
  const int* d1 = (const int*)d_in[6];
  const int* d2 = (const int*)d_in[7];
  const int* d3 = (const int*)d_in[8];
  const int* d4 = (const int*)d_in[9];
  const int* u1p = (const int*)d_in[10]; const int* u1o = (const int*)d_in[11];
  const int* u2p = (const int*)d_in[12]; const int* u2o = (const int*)d_in[13];
  const int* u3p = (const int*)d_in[14]; const int* u3o = (const int*)d_in[15];
  const int* u4p = (const int*)d_in[16]; const int* u4o = (const int*)d_in[17];
  const void* params = d_in[18];
  (void)in_sizes; (void)n_in;

  static PrepD h_table[64];
  long totalC = 0, totalE = 0;
  int NL = build_table(h_table, &totalC, &totalE);

  char* base = (char*)d_ws; size_t off = 0;
  auto ab = [&](size_t bytes) -> void* { void* p = base + off; off += (bytes + 63) & ~(size_t)63; return p; };
  int* flagp = (int*)ab(64);
  float* st = (float*)ab((size_t)64 * 768 * 4);
  float* Bstf = (float*)ab((size_t)512 * 4);  // fp32 bias staging
  float* x0 = (float*)ab((size_t)NP0 * 32 * 4);
  float* x1 = (float*)ab((size_t)NP1 * 32 * 4);
  float* x2 = (float*)ab((size_t)NP2 * 64 * 4);
  float* x3 = (float*)ab((size_t)NP3 * 128 * 4);
  float* x4 = (float*)ab((size_t)NP4 * 256 * 4);
  float* U  = (float*)ab((size_t)NP0 * 96 * 4);
  float* A  = (float*)ab((size_t)NP0 * 96 * 4);
  float* B  = (float*)ab((size_t)NP0 * 128 * 4);
  float* Xp = B;  // overlay: Xp dead before B's first use

  // weight staging: one-shot full prep if workspace allows, else per-layer
  size_t wall_bytes = (size_t)totalE * 4;   // hi+lo planes, 2 B each
  size_t rem = (ws_size > off) ? (ws_size - off) : 0;
  bool bigprep = rem >= wall_bytes + 8192;
  u16* Wall = nullptr; PrepD* d_table = nullptr; u16* Wst = nullptr;
  if (bigprep) {
    Wall = (u16*)ab(wall_bytes);
    d_table = (PrepD*)ab(4096);
  } else {
    Wst = (u16*)ab((size_t)5400000 * 2);
  }
  if (off > ws_size) { hipMemsetAsync(d_out, 0, (size_t)out_size * 2, stream); return; }

  long po = 0;   // param element cursor
  int bnc = 0;   // BN slot cursor
  int wli = 0;   // weight-layer index (bigprep)

  auto prepF = [&](int K, int CI, int CO, int CB32, int NT16) -> long {
    long chunks = (long)K * CB32 * NT16 * 64;
    long halfel = chunks * 8;
    int nb = (int)((chunks + 255) / 256); if (nb > 4096) nb = 4096; if (nb < 1) nb = 1;
    k_prep_frag<<<nb, 256, 0, stream>>>(params, flagp, Wst, po, halfel, K, CI, CO, CB32, NT16);
    po += (long)K * CI * CO;
    return halfel;
  };
  auto getW = [&](int K, int CI, int CO, int CB32, int NT16, const u16** Wp, long* he) {
    if (bigprep) {
      *Wp = Wall + h_table[wli].dst; *he = totalE;
      ++wli; po += (long)K * CI * CO;
    } else {
      *he = prepF(K, CI, CO, CB32, NT16); *Wp = Wst;
    }
  };
  auto convop = [&](const float* X, const int* nb_, int K, int CI, int CO, float* Y, int N, int XS) {
    int CB32 = cdiv(CI, 32), NT16 = cdiv(CO, 16);
    const u16* Wp; long he;
    getW(K, CI, CO, CB32, NT16, &Wp, &he);
    launch_conv(stream, cdiv(N, 128), X, nb_, Wp, he, Y, nullptr, 0, flagp, N, K, CB32, NT16, CO, XS);
  };
  auto linop = [&](const float* X, int CI, int CO, float* Y, int N, bool bias, int relu) {
    int CB32 = cdiv(CI, 32), NT16 = cdiv(CO, 16);
    const u16* Wp; long he;
    getW(1, CI, CO, CB32, NT16, &Wp, &he);
    const float* bp = nullptr;
    if (bias) {
      k_prep_bias<<<cdiv(CO, 256), 256, 0, stream>>>(params, flagp, Bstf, po, CO);
      po += CO; bp = Bstf;
    }
    launch_conv(stream, cdiv(N, 128), X, nullptr, Wp, he, Y, bp, relu, flagp, N, 1, CB32, NT16, CO, CI);
  };
  auto deconvop = [&](const float* X, const int* par, const int* ofv, int CI, int CO, float* Y, int N) {
    long wofs = po; po += (long)8 * CI * CO;
    dim3 g(cdiv(CO, 64), cdiv(N, 4));
    k_deconv<<<g, 256, 0, stream>>>(X, par, ofv, params, wofs, flagp, Y, N, CI, CO);
  };
  auto bnop = [&](const float* X, int N, int C, const float* add, int relu, float* out) {
    float* slot = st + (size_t)(bnc++) * 768;
    int total = N * C;
    int total4 = total >> 2;
    int nb1 = cdiv(total4, 4096); if (nb1 > 504) nb1 = 504; if (nb1 < 3) nb1 = 3;
    nb1 = ((nb1 + 2) / 3) * 3;
    k_bn_stats<<<nb1, 256, 0, stream>>>(X, slot, total, C);
    int nb2 = cdiv(total4, 2048); if (nb2 > 510) nb2 = 510; if (nb2 < 3) nb2 = 3;
    nb2 = ((nb2 + 2) / 3) * 3;
    k_bn_apply<<<nb2, 256, 0, stream>>>(X, slot, add, out ? out : (float*)X, relu, total, C, 1.0f / (float)N);
  };
  auto copyop = [&](const float* S, float* D, int N, int Cs, int Cd, int o2) {
    int total4 = (N * Cs) >> 2;
    int nb3 = cdiv(total4, 1024); if (nb3 > 1024) nb3 = 1024; if (nb3 < 1) nb3 = 1;
    k_copycols<<<nb3, 256, 0, stream>>>(S, D, N, Cs, Cd, o2);
  };
  auto storeop = [&](const float* S, size_t eo, int n) {
    int nb4 = cdiv(n >> 2, 1024); if (nb4 > 1024) nb4 = 1024; if (nb4 < 1) nb4 = 1;
    k_store_dyn<<<nb4, 256, 0, stream>>>(S, d_out, flagp, eo, n);
  };
  auto resblock = [&](const int* nb, int N, int CI, int CO,
                      float* H, float* t1, float* t2, float* OUT) {
    convop(H, nb, 27, CI, CO, t1, N, CI);
    bnop(t1, N, CO, nullptr, 1, nullptr);
    convop(t1, nb, 27, CO, CO, t2, N, CO);
    const float* S;
    if (CI == CO) S = H;
    else { linop(H, CI, CO, t1, N, false, 0); bnop(t1, N, CO, nullptr, 0, nullptr); S = t1; }
    bnop(t2, N, CO, S, 1, OUT);
  };

  k_sniff<<<1, 256, 0, stream>>>(xraw, flagp);
  if (bigprep) {
    hipMemcpyAsync(d_table, h_table, (size_t)NL * sizeof(PrepD), hipMemcpyHostToDevice, stream);
    int nbp = (int)((totalC + 255) / 256); if (nbp > 4096) nbp = 4096;
    k_prep_all<<<nbp, 256, 0, stream>>>(params, flagp, Wall, d_table, NL, totalC, totalE);
  }
  hipMemsetAsync(st, 0, (size_t)64 * 768 * 4, stream);
  k_pad<<<1024, 256, 0, stream>>>(xraw, flagp, Xp, NP0);

  // stem
  convop(Xp, nbr0, 27, 4, 32, A, NP0, 32);  bnop(A, NP0, 32, nullptr, 1, nullptr);
  convop(A, nbr0, 27, 32, 32, x0, NP0, 32); bnop(x0, NP0, 32, nullptr, 1, nullptr);
  // stage1
  convop(x0, d1, 8, 32, 32, U, NP1, 32); bnop(U, NP1, 32, nullptr, 1, nullptr);
  resblock(nbr1, NP1, 32, 32, U, A, B, U);
  resblock(nbr1, NP1, 32, 32, U, A, B, x1);
  // stage2
  convop(x1, d2, 8, 32, 32, U, NP2, 32); bnop(U, NP2, 32, nullptr, 1, nullptr);
  resblock(nbr2, NP2, 32, 64, U, A, B, U);
  resblock(nbr2, NP2, 64, 64, U, A, B, x2);
  // stage3
  convop(x2, d3, 8, 64, 64, U, NP3, 64); bnop(U, NP3, 64, nullptr, 1, nullptr);
  resblock(nbr3, NP3, 64, 128, U, A, B, U);
  resblock(nbr3, NP3, 128, 128, U, A, B, x3);
  // stage4
  convop(x3, d4, 8, 128, 128, U, NP4, 128); bnop(U, NP4, 128, nullptr, 1, nullptr);
  resblock(nbr4, NP4, 128, 256, U, A, B, U);
  resblock(nbr4, NP4, 256, 256, U, A, B, x4);
  // up1
  deconvop(x4, u1p, u1o, 256, 256, A, NP3); bnop(A, NP3, 256, nullptr, 1, nullptr);
  copyop(A, B, NP3, 256, 384, 0); copyop(x3, B, NP3, 128, 384, 256);
  resblock(nbr3, NP3, 384, 256, B, A, U, B);
  resblock(nbr3, NP3, 256, 256, B, A, U, U);
  // up2
  deconvop(U, u2p, u2o, 256, 128, A, NP2); bnop(A, NP2, 128, nullptr, 1, nullptr);
  copyop(A, B, NP2, 128, 192, 0); copyop(x2, B, NP2, 64, 192, 128);
  resblock(nbr2, NP2, 192, 128, B, A, U, B);
  resblock(nbr2, NP2, 128, 128, B, A, U, U);
  // up3
  deconvop(U, u3p, u3o, 128, 96, A, NP1); bnop(A, NP1, 96, nullptr, 1, nullptr);
  copyop(A, B, NP1, 96, 128, 0); copyop(x1, B, NP1, 32, 128, 96);
  resblock(nbr1, NP1, 128, 96, B, A, U, B);
  resblock(nbr1, NP1, 96, 96, B, A, U, U);
  // up4
  deconvop(U, u4p, u4o, 96, 96, A, NP0); bnop(A, NP0, 96, nullptr, 1, nullptr);
  copyop(A, B, NP0, 96, 128, 0); copyop(x0, B, NP0, 32, 128, 96);
  resblock(nbr0, NP0, 128, 96, B, A, U, B);
  resblock(nbr0, NP0, 96, 96, B, A, U, U);
  // head: logits -> x0 region (dead), t -> A, feat -> B
  linop(U, 96, 19, x0, NP0, true, 0);
  linop(U, 96, 96, A, NP0, true, 1);
  linop(A, 96, 128, B, NP0, true, 0);
  storeop(x0, 0, NP0 * 19);
  storeop(B, (size_t)NP0 * 19, NP0 * 128);
}

// Round 10
// 4015.081 us; speedup vs baseline: 1.2133x; 1.2133x over previous
//
#include <hip/hip_runtime.h>
#include <hip/hip_bf16.h>
#include <stdint.h>

typedef __hip_bfloat16 hbf;
typedef unsigned short u16;
typedef __attribute__((ext_vector_type(8))) short bfrag;      // 8 bf16
typedef _Float16 __attribute__((ext_vector_type(8))) hfrag;   // 8 fp16
typedef __attribute__((ext_vector_type(4))) float f4;         // 16x16 accumulator

#define NP0 50000
#define NP1 20000
#define NP2 8000
#define NP3 3200
#define NP4 1300

static inline int cdiv(int a, int b) { return (a + b - 1) / b; }

static __device__ __forceinline__ float u2f(u16 u) { return __uint_as_float(((unsigned)u) << 16); }
static __device__ __forceinline__ u16 f2u(float f) {
  hbf h = __float2bfloat16(f);
  u16 r; __builtin_memcpy(&r, &h, 2); return r;
}
static __device__ __forceinline__ u16 f2h(float f) {
  _Float16 h = (_Float16)f;
  u16 r; __builtin_memcpy(&r, &h, 2); return r;
}
static __device__ __forceinline__ float h2f(u16 u) {
  _Float16 h; __builtin_memcpy(&h, &u, 2); return (float)h;
}
static __device__ __forceinline__ float pload(const void* P, int isbf, size_t i) {
  return isbf ? u2f(((const u16*)P)[i]) : ((const float*)P)[i];
}

// Encoder activations: fp32 (deep error-compounding path needs precision).
// Decoder (up1..up4 + head) activations: fp16 (2^-12 rounding, <=12 layers of
// compounding, halves gather traffic). Weights: encoder bf16 hi/lo planes,
// decoder fp16 hi/lo planes. On a bf16 wire both lo planes are exactly zero
// (bf16 values are exactly representable), so lo passes are skipped.

struct PrepD {
  long cpre, src, dst;
  int K, CI, CO, CB32, NT16, hf;
};

__global__ void k_sniff(const void* __restrict__ xraw, int* __restrict__ flagp) {
  __shared__ float smax[256];
  const u16* u = (const u16*)xraw;
  float m = 0.f;
  for (int i = threadIdx.x; i < 2048; i += 256) {
    float v = u2f(u[2 * i]);
    if (isnan(v) || isinf(v)) m = 1e30f; else m = fmaxf(m, fabsf(v));
  }
  smax[threadIdx.x] = m;
  __syncthreads();
  for (int s = 128; s > 0; s >>= 1) {
    if (threadIdx.x < s) smax[threadIdx.x] = fmaxf(smax[threadIdx.x], smax[threadIdx.x + s]);
    __syncthreads();
  }
  if (threadIdx.x == 0) *flagp = (smax[0] < 1e4f) ? 1 : 0;
}

__global__ __launch_bounds__(256) void k_prep_all(
    const void* __restrict__ P, const int* __restrict__ flagp, u16* __restrict__ W,
    const PrepD* __restrict__ T, int NL, long totalC, long totalE)
{
  int f = *flagp;
  int L = 0;
  for (long c = (long)blockIdx.x * 256 + threadIdx.x; c < totalC; c += (long)gridDim.x * 256) {
    while (L + 1 < NL && c >= T[L + 1].cpre) ++L;
    PrepD d = T[L];
    long lc = c - d.cpre;
    int lane = (int)(lc & 63); long t = lc >> 6;
    int nt = (int)(t % d.NT16); t /= d.NT16;
    int cb = (int)(t % d.CB32); int k = (int)(t / d.CB32);
    int co = nt * 16 + (lane & 15);
    int cib = cb * 32 + (lane >> 4) * 8;
    u16 hi[8], lo[8];
#pragma unroll
    for (int j = 0; j < 8; ++j) {
      int ci = cib + j; float v = 0.f;
      if (ci < d.CI && co < d.CO) v = pload(P, f, d.src + ((size_t)k * d.CI + ci) * d.CO + co);
      if (d.hf) { u16 h = f2h(v); hi[j] = h; lo[j] = f2h(v - h2f(h)); }
      else      { u16 h = f2u(v); hi[j] = h; lo[j] = f2u(v - u2f(h)); }
    }
    *(bfrag*)(W + d.dst + lc * 8) = *(const bfrag*)hi;
    *(bfrag*)(W + totalE + d.dst + lc * 8) = *(const bfrag*)lo;
  }
}

__global__ __launch_bounds__(256) void k_prep_frag(
    const void* __restrict__ P, const int* __restrict__ flagp, u16* __restrict__ W,
    long src, long halfel, int hf, int K, int CI, int CO, int CB32, int NT16)
{
  int f = *flagp;
  long total = (long)K * CB32 * NT16 * 64;
  for (long c = (long)blockIdx.x * 256 + threadIdx.x; c < total; c += (long)gridDim.x * 256) {
    int lane = (int)(c & 63); long t = c >> 6;
    int nt = (int)(t % NT16); t /= NT16;
    int cb = (int)(t % CB32); int k = (int)(t / CB32);
    int co = nt * 16 + (lane & 15);
    int cib = cb * 32 + (lane >> 4) * 8;
    u16 hi[8], lo[8];
#pragma unroll
    for (int j = 0; j < 8; ++j) {
      int ci = cib + j; float v = 0.f;
      if (ci < CI && co < CO) v = pload(P, f, src + ((size_t)k * CI + ci) * CO + co);
      if (hf) { u16 h = f2h(v); hi[j] = h; lo[j] = f2h(v - h2f(h)); }
      else    { u16 h = f2u(v); hi[j] = h; lo[j] = f2u(v - u2f(h)); }
    }
    *(bfrag*)(W + c * 8) = *(const bfrag*)hi;
    *(bfrag*)(W + halfel + c * 8) = *(const bfrag*)lo;
  }
}

__global__ void k_prep_bias(const void* __restrict__ P, const int* __restrict__ flagp,
                            float* __restrict__ B, long src, int n)
{
  int f = *flagp;
  int i = blockIdx.x * 256 + threadIdx.x;
  if (i < n) B[i] = pload(P, f, src + i);
}

__global__ void k_pad(const void* __restrict__ xraw, const int* __restrict__ flagp,
                      float* __restrict__ Xp, int N)
{
  int f = *flagp; int total = N * 32;
  for (int i = blockIdx.x * 256 + threadIdx.x; i < total; i += gridDim.x * 256) {
    int n = i >> 5, cc = i & 31;
    Xp[i] = (cc < 4) ? pload(xraw, f, (size_t)n * 4 + cc) : 0.f;
  }
}

// ---- MFMA gather-GEMM, reduction-split over gridDim.z ----
template<int NT>
__global__ __launch_bounds__(256) void k_conv_mfma(
    const void* __restrict__ Xv, const int* __restrict__ nbr,
    const u16* __restrict__ Wp, long halfel, float* __restrict__ Y,
    const float* __restrict__ bias, int relu, const int* __restrict__ flagp,
    int ahalf, int N, int K, int CB32, int NT16, int CO, int XS, int tlen, int atomic)
{
  const int f = *flagp;
  const int lane = threadIdx.x & 63;
  const int wv = threadIdx.x >> 6;
  const int rowbase = blockIdx.x * 128 + wv * 32;
  const int ntb = blockIdx.y * NT;
  const int ml = lane & 15;
  const int quad = lane >> 4;
  const int ktot = K * CB32;
  const int t0 = blockIdx.z * tlen;
  const int t1 = (t0 + tlen < ktot) ? (t0 + tlen) : ktot;
  if (t0 >= t1) return;

  f4 acc[2][NT];
#pragma unroll
  for (int i = 0; i < 2; ++i)
#pragma unroll
    for (int j = 0; j < NT; ++j) acc[i][j] = (f4)(0.f);

  int k = t0 / CB32;
  int cb = t0 - k * CB32;
  int idx[2];
  bool fresh = true;

  if (ahalf) {
    const u16* X = (const u16*)Xv;
    if (f) {
      for (int t = t0; t < t1; ++t) {
        if (fresh) {
#pragma unroll
          for (int mt = 0; mt < 2; ++mt) {
            int r = rowbase + mt * 16 + ml;
            idx[mt] = (r < N) ? (nbr ? nbr[(size_t)r * K + k] : r) : 0;
          }
          fresh = false;
        }
        const u16* WH = Wp + (size_t)t * NT16 * 512;
        hfrag bh[NT];
#pragma unroll
        for (int nt = 0; nt < NT; ++nt)
          bh[nt] = *(const hfrag*)(WH + ((size_t)(ntb + nt) * 64 + lane) * 8);
        hfrag a[2];
#pragma unroll
        for (int mt = 0; mt < 2; ++mt)
          a[mt] = *(const hfrag*)(X + (size_t)idx[mt] * XS + cb * 32 + quad * 8);
#pragma unroll
        for (int mt = 0; mt < 2; ++mt)
#pragma unroll
          for (int nt = 0; nt < NT; ++nt)
            acc[mt][nt] = __builtin_amdgcn_mfma_f32_16x16x32_f16(a[mt], bh[nt], acc[mt][nt], 0, 0, 0);
        if (++cb == CB32) { cb = 0; ++k; fresh = true; }
      }
    } else {
      for (int t = t0; t < t1; ++t) {
        if (fresh) {
#pragma unroll
          for (int mt = 0; mt < 2; ++mt) {
            int r = rowbase + mt * 16 + ml;
            idx[mt] = (r < N) ? (nbr ? nbr[(size_t)r * K + k] : r) : 0;
          }
          fresh = false;
        }
        const u16* WH = Wp + (size_t)t * NT16 * 512;
        const u16* WL = WH + halfel;
        hfrag bh[NT], bl[NT];
#pragma unroll
        for (int nt = 0; nt < NT; ++nt) {
          size_t o = ((size_t)(ntb + nt) * 64 + lane) * 8;
          bh[nt] = *(const hfrag*)(WH + o);
          bl[nt] = *(const hfrag*)(WL + o);
        }
        hfrag a[2];
#pragma unroll
        for (int mt = 0; mt < 2; ++mt)
          a[mt] = *(const hfrag*)(X + (size_t)idx[mt] * XS + cb * 32 + quad * 8);
#pragma unroll
        for (int mt = 0; mt < 2; ++mt)
#pragma unroll
          for (int nt = 0; nt < NT; ++nt) {
            acc[mt][nt] = __builtin_amdgcn_mfma_f32_16x16x32_f16(a[mt], bl[nt], acc[mt][nt], 0, 0, 0);
            acc[mt][nt] = __builtin_amdgcn_mfma_f32_16x16x32_f16(a[mt], bh[nt], acc[mt][nt], 0, 0, 0);
          }
        if (++cb == CB32) { cb = 0; ++k; fresh = true; }
      }
    }
  } else {
    const float* X = (const float*)Xv;
    if (f) {
      for (int t = t0; t < t1; ++t) {
        if (fresh) {
#pragma unroll
          for (int mt = 0; mt < 2; ++mt) {
            int r = rowbase + mt * 16 + ml;
            idx[mt] = (r < N) ? (nbr ? nbr[(size_t)r * K + k] : r) : 0;
          }
          fresh = false;
        }
        const u16* WH = Wp + (size_t)t * NT16 * 512;
        bfrag bh[NT];
#pragma unroll
        for (int nt = 0; nt < NT; ++nt)
          bh[nt] = *(const bfrag*)(WH + ((size_t)(ntb + nt) * 64 + lane) * 8);
        bfrag ahi[2], alo[2];
#pragma unroll
        for (int mt = 0; mt < 2; ++mt) {
          const float* ap = X + (size_t)idx[mt] * XS + cb * 32 + quad * 8;
          float4 q0 = *(const float4*)ap;
          float4 q1 = *(const float4*)(ap + 4);
          float av[8] = {q0.x, q0.y, q0.z, q0.w, q1.x, q1.y, q1.z, q1.w};
          u16 hi8[8], lo8[8];
#pragma unroll
          for (int j = 0; j < 8; ++j) {
            u16 hh = f2u(av[j]);
            hi8[j] = hh;
            lo8[j] = f2u(av[j] - u2f(hh));
          }
          __builtin_memcpy(&ahi[mt], hi8, 16);
          __builtin_memcpy(&alo[mt], lo8, 16);
        }
#pragma unroll
        for (int mt = 0; mt < 2; ++mt)
#pragma unroll
          for (int nt = 0; nt < NT; ++nt) {
            acc[mt][nt] = __builtin_amdgcn_mfma_f32_16x16x32_bf16(alo[mt], bh[nt], acc[mt][nt], 0, 0, 0);
            acc[mt][nt] = __builtin_amdgcn_mfma_f32_16x16x32_bf16(ahi[mt], bh[nt], acc[mt][nt], 0, 0, 0);
          }
        if (++cb == CB32) { cb = 0; ++k; fresh = true; }
      }
    } else {
      for (int t = t0; t < t1; ++t) {
        if (fresh) {
#pragma unroll
          for (int mt = 0; mt < 2; ++mt) {
            int r = rowbase + mt * 16 + ml;
            idx[mt] = (r < N) ? (nbr ? nbr[(size_t)r * K + k] : r) : 0;
          }
          fresh = false;
        }
        const u16* WH = Wp + (size_t)t * NT16 * 512;
        const u16* WL = WH + halfel;
        bfrag bh[NT], bl[NT];
#pragma unroll
        for (int nt = 0; nt < NT; ++nt) {
          size_t o = ((size_t)(ntb + nt) * 64 + lane) * 8;
          bh[nt] = *(const bfrag*)(WH + o);
          bl[nt] = *(const bfrag*)(WL + o);
        }
        bfrag ahi[2], alo[2];
#pragma unroll
        for (int mt = 0; mt < 2; ++mt) {
          const float* ap = X + (size_t)idx[mt] * XS + cb * 32 + quad * 8;
          float4 q0 = *(const float4*)ap;
          float4 q1 = *(const float4*)(ap + 4);
          float av[8] = {q0.x, q0.y, q0.z, q0.w, q1.x, q1.y, q1.z, q1.w};
          u16 hi8[8], lo8[8];
#pragma unroll
          for (int j = 0; j < 8; ++j) {
            u16 hh = f2u(av[j]);
            hi8[j] = hh;
            lo8[j] = f2u(av[j] - u2f(hh));
          }
          __builtin_memcpy(&ahi[mt], hi8, 16);
          __builtin_memcpy(&alo[mt], lo8, 16);
        }
#pragma unroll
        for (int mt = 0; mt < 2; ++mt)
#pragma unroll
          for (int nt = 0; nt < NT; ++nt) {
            acc[mt][nt] = __builtin_amdgcn_mfma_f32_16x16x32_bf16(alo[mt], bh[nt], acc[mt][nt], 0, 0, 0);
            acc[mt][nt] = __builtin_amdgcn_mfma_f32_16x16x32_bf16(ahi[mt], bl[nt], acc[mt][nt], 0, 0, 0);
            acc[mt][nt] = __builtin_amdgcn_mfma_f32_16x16x32_bf16(ahi[mt], bh[nt], acc[mt][nt], 0, 0, 0);
          }
        if (++cb == CB32) { cb = 0; ++k; fresh = true; }
      }
    }
  }

#pragma unroll
  for (int mt = 0; mt < 2; ++mt) {
#pragma unroll
    for (int nt = 0; nt < NT; ++nt) {
      int col = (ntb + nt) * 16 + ml;
      if (col >= CO) continue;
      float bvv = bias ? bias[col] : 0.f;
#pragma unroll
      for (int reg = 0; reg < 4; ++reg) {
        int row = rowbase + mt * 16 + quad * 4 + reg;
        if (row < N) {
          if (atomic) {
            atomicAdd(&Y[(size_t)row * CO + col], acc[mt][nt][reg]);
          } else {
            float v = acc[mt][nt][reg] + bvv;
            if (relu) v = fmaxf(v, 0.f);
            Y[(size_t)row * CO + col] = v;
          }
        }
      }
    }
  }
}

__global__ void k_bias_relu(float* __restrict__ Y, const float* __restrict__ bias,
                            u16* __restrict__ d16, int relu, int total, int CO)
{
  int stride = gridDim.x * 256;
  for (int i = blockIdx.x * 256 + threadIdx.x; i < total; i += stride) {
    int c = i % CO;
    float v = Y[i] + (bias ? bias[c] : 0.f);
    if (relu) v = fmaxf(v, 0.f);
    Y[i] = v;
    if (d16) d16[i] = f2h(v);
  }
}

static void launch_conv(hipStream_t s, int bx, const void* X, const int* nbr,
                        const u16* W, long halfel, float* Y, const float* bias, int relu,
                        const int* flagp, int ahalf, int N, int K, int CB32, int NT16, int CO, int XS,
                        u16* d16)
{
  int NT = (NT16 % 6 == 0) ? 6 : ((NT16 % 4 == 0) ? 4 : 2);
  int ny = NT16 / NT;
  int ktot = K * CB32;
  long blocks = (long)bx * ny;
  int ZS = 1;
  if (ktot > 1) {
    ZS = (int)((1024 + blocks - 1) / blocks);
    if (ZS > ktot) ZS = ktot;
    if (ZS < 1) ZS = 1;
  }
  int tlen = cdiv(ktot, ZS);
  ZS = cdiv(ktot, tlen);
  int atomic = (ZS > 1) ? 1 : 0;
  if (atomic) hipMemsetAsync(Y, 0, (size_t)N * CO * 4, s);
  dim3 g(bx, ny, ZS);
  if (NT == 6)      k_conv_mfma<6><<<g, 256, 0, s>>>(X, nbr, W, halfel, Y, bias, relu, flagp, ahalf, N, K, CB32, NT16, CO, XS, tlen, atomic);
  else if (NT == 4) k_conv_mfma<4><<<g, 256, 0, s>>>(X, nbr, W, halfel, Y, bias, relu, flagp, ahalf, N, K, CB32, NT16, CO, XS, tlen, atomic);
  else              k_conv_mfma<2><<<g, 256, 0, s>>>(X, nbr, W, halfel, Y, bias, relu, flagp, ahalf, N, K, CB32, NT16, CO, XS, tlen, atomic);
  if ((atomic && (bias || relu)) || d16) {
    int total = N * CO;
    int nb = cdiv(total, 1024); if (nb > 1024) nb = 1024; if (nb < 1) nb = 1;
    k_bias_relu<<<nb, 256, 0, s>>>(Y, atomic ? bias : nullptr, d16, atomic ? relu : 0, total, CO);
  }
}

__global__ __launch_bounds__(256) void k_deconv(
    const void* __restrict__ Xv, const int* __restrict__ par, const int* __restrict__ off,
    const void* __restrict__ P, long wofs, const int* __restrict__ flagp,
    float* __restrict__ Y, int xmode, int N, int CI, int CO)
{
  int f = *flagp;
  int lane = threadIdx.x & 63, wv = threadIdx.x >> 6;
  int n = blockIdx.y * 4 + wv; if (n >= N) return;
  int co = blockIdx.x * 64 + lane; if (co >= CO) return;
  size_t wbase = wofs + (size_t)off[n] * CI * CO + co;
  float acc = 0.f;
  if (xmode) {
    const u16* xr = (const u16*)Xv + (size_t)par[n] * CI;
    for (int ci = 0; ci < CI; ci += 4) {
      ushort4 xv = *(const ushort4*)(xr + ci);
      acc += h2f(xv.x) * pload(P, f, wbase + (size_t)ci * CO);
      acc += h2f(xv.y) * pload(P, f, wbase + (size_t)(ci + 1) * CO);
      acc += h2f(xv.z) * pload(P, f, wbase + (size_t)(ci + 2) * CO);
      acc += h2f(xv.w) * pload(P, f, wbase + (size_t)(ci + 3) * CO);
    }
  } else {
    const float* xr = (const float*)Xv + (size_t)par[n] * CI;
    for (int ci = 0; ci < CI; ci += 4) {
      float4 xv = *(const float4*)(xr + ci);
      acc += xv.x * pload(P, f, wbase + (size_t)ci * CO);
      acc += xv.y * pload(P, f, wbase + (size_t)(ci + 1) * CO);
      acc += xv.z * pload(P, f, wbase + (size_t)(ci + 2) * CO);
      acc += xv.w * pload(P, f, wbase + (size_t)(ci + 3) * CO);
    }
  }
  Y[(size_t)n * CO + co] = acc;
}

__global__ __launch_bounds__(256) void k_bn_stats(
    const float* __restrict__ X, float* __restrict__ st, int total, int C)
{
  __shared__ float ssum[384], ssq[384];
  for (int c = threadIdx.x; c < C; c += 256) { ssum[c] = 0.f; ssq[c] = 0.f; }
  __syncthreads();
  int gid = blockIdx.x * 256 + threadIdx.x;
  int total4 = total >> 2;
  int stride = gridDim.x * 256;
  int c0 = (gid * 4) % C;
  float s0 = 0.f, s1 = 0.f, s2 = 0.f, s3 = 0.f;
  float q0 = 0.f, q1 = 0.f, q2 = 0.f, q3 = 0.f;
  for (int i = gid; i < total4; i += stride) {
    float4 v = ((const float4*)X)[i];
    s0 += v.x; q0 += v.x * v.x;
    s1 += v.y; q1 += v.y * v.y;
    s2 += v.z; q2 += v.z * v.z;
    s3 += v.w; q3 += v.w * v.w;
  }
  atomicAdd(&ssum[c0], s0);     atomicAdd(&ssq[c0], q0);
  atomicAdd(&ssum[c0 + 1], s1); atomicAdd(&ssq[c0 + 1], q1);
  atomicAdd(&ssum[c0 + 2], s2); atomicAdd(&ssq[c0 + 2], q2);
  atomicAdd(&ssum[c0 + 3], s3); atomicAdd(&ssq[c0 + 3], q3);
  __syncthreads();
  for (int c = threadIdx.x; c < C; c += 256) {
    atomicAdd(&st[c], ssum[c]); atomicAdd(&st[384 + c], ssq[c]);
  }
}

__global__ __launch_bounds__(256) void k_bn_apply(
    const float* __restrict__ X, const float* __restrict__ st,
    const void* __restrict__ addp, int addmode,
    void* __restrict__ Yo, int outmode, int relu, int total, int C, float invN)
{
  __shared__ float mean[384], rsig[384];
  for (int c = threadIdx.x; c < C; c += 256) {
    float mm = st[c] * invN;
    float vv = st[384 + c] * invN - mm * mm;
    mean[c] = mm; rsig[c] = rsqrtf(vv + 1e-5f);
  }
  __syncthreads();
  int gid = blockIdx.x * 256 + threadIdx.x;
  int total4 = total >> 2;
  int stride = gridDim.x * 256;
  int c0 = (gid * 4) % C;
  float m0 = mean[c0], m1 = mean[c0 + 1], m2 = mean[c0 + 2], m3 = mean[c0 + 3];
  float r0 = rsig[c0], r1 = rsig[c0 + 1], r2 = rsig[c0 + 2], r3 = rsig[c0 + 3];
  for (int i = gid; i < total4; i += stride) {
    float4 v = ((const float4*)X)[i];
    float w0 = (v.x - m0) * r0, w1 = (v.y - m1) * r1;
    float w2 = (v.z - m2) * r2, w3 = (v.w - m3) * r3;
    if (addmode == 1) {
      float4 a = ((const float4*)addp)[i];
      w0 += a.x; w1 += a.y; w2 += a.z; w3 += a.w;
    } else if (addmode == 2) {
      ushort4 ah = *(const ushort4*)((const u16*)addp + (size_t)i * 4);
      w0 += h2f(ah.x); w1 += h2f(ah.y); w2 += h2f(ah.z); w3 += h2f(ah.w);
    }
    if (relu) {
      w0 = fmaxf(w0, 0.f); w1 = fmaxf(w1, 0.f);
      w2 = fmaxf(w2, 0.f); w3 = fmaxf(w3, 0.f);
    }
    if (outmode == 0) {
      float4 o; o.x = w0; o.y = w1; o.z = w2; o.w = w3;
      ((float4*)Yo)[i] = o;
    } else {
      ushort4 hh; hh.x = f2h(w0); hh.y = f2h(w1); hh.z = f2h(w2); hh.w = f2h(w3);
      *(ushort4*)((u16*)Yo + (size_t)i * 4) = hh;
    }
  }
}

__global__ void k_copycols(const void* __restrict__ Sv, u16* __restrict__ D,
                           int smode, int N, int Cs, int Cd, int off)
{
  int csq = Cs >> 2;
  int total4 = N * csq;
  int stride = gridDim.x * 256;
  for (int i = blockIdx.x * 256 + threadIdx.x; i < total4; i += stride) {
    int n = i / csq, cc = (i - n * csq) * 4;
    ushort4 hh;
    if (smode == 0) {
      float4 v = ((const float4*)Sv)[i];
      hh.x = f2h(v.x); hh.y = f2h(v.y); hh.z = f2h(v.z); hh.w = f2h(v.w);
    } else {
      hh = *(const ushort4*)((const u16*)Sv + (size_t)i * 4);
    }
    *(ushort4*)(D + (size_t)n * Cd + off + cc) = hh;
  }
}

__global__ void k_store_dyn(const float* __restrict__ S, void* __restrict__ D,
                            const int* __restrict__ flagp, size_t eofs, int n)
{
  int f = *flagp;
  int n4 = n >> 2;
  int stride = gridDim.x * 256;
  for (int i = blockIdx.x * 256 + threadIdx.x; i < n4; i += stride) {
    float4 v = ((const float4*)S)[i];
    if (f) {
      ushort4 u;
      u.x = f2u(v.x); u.y = f2u(v.y); u.z = f2u(v.z); u.w = f2u(v.w);
      *(ushort4*)((u16*)D + eofs + (size_t)i * 4) = u;
    } else {
      *(float4*)((float*)D + eofs + (size_t)i * 4) = v;
    }
  }
}

static int build_table(PrepD* T, long* totalC, long* totalE) {
  int n = 0; long po = 0, ce = 0, cc = 0;
  auto W = [&](int K, int CI, int CO, int hf) {
    int CB = cdiv(CI, 32), NTx = cdiv(CO, 16);
    long ch = (long)K * CB * NTx * 64;
    T[n].cpre = cc; T[n].src = po; T[n].dst = ce;
    T[n].K = K; T[n].CI = CI; T[n].CO = CO; T[n].CB32 = CB; T[n].NT16 = NTx; T[n].hf = hf;
    ++n; cc += ch; ce += ch * 8; po += (long)K * CI * CO;
  };
  auto SKIP = [&](long e) { po += e; };
  W(27, 4, 32, 0); W(27, 32, 32, 0);
  W(8, 32, 32, 0); W(27, 32, 32, 0); W(27, 32, 32, 0); W(27, 32, 32, 0); W(27, 32, 32, 0);
  W(8, 32, 32, 0); W(27, 32, 64, 0); W(27, 64, 64, 0); W(1, 32, 64, 0); W(27, 64, 64, 0); W(27, 64, 64, 0);
  W(8, 64, 64, 0); W(27, 64, 128, 0); W(27, 128, 128, 0); W(1, 64, 128, 0); W(27, 128, 128, 0); W(27, 128, 128, 0);
  W(8, 128, 128, 0); W(27, 128, 256, 0); W(27, 256, 256, 0); W(1, 128, 256, 0); W(27, 256, 256, 0); W(27, 256, 256, 0);
  SKIP(8L * 256 * 256);
  W(27, 384, 256, 1); W(27, 256, 256, 1); W(1, 384, 256, 1); W(27, 256, 256, 1); W(27, 256, 256, 1);
  SKIP(8L * 256 * 128);
  W(27, 192, 128, 1); W(27, 128, 128, 1); W(1, 192, 128, 1); W(27, 128, 128, 1); W(27, 128, 128, 1);
  SKIP(8L * 128 * 96);
  W(27, 128, 96, 1); W(27, 96, 96, 1); W(1, 128, 96, 1); W(27, 96, 96, 1); W(27, 96, 96, 1);
  SKIP(8L * 96 * 96);
  W(27, 128, 96, 1); W(27, 96, 96, 1); W(1, 128, 96, 1); W(27, 96, 96, 1); W(27, 96, 96, 1);
  W(1, 96, 19, 1); SKIP(19); W(1, 96, 96, 1); SKIP(96); W(1, 96, 128, 1); SKIP(128);
  *totalC = cc; *totalE = ce;
  return n;
}

extern "C" void kernel_launch(void* const* d_in, const int* in_sizes, int n_in,
                              void* d_out, int out_size, void* d_ws, size_t ws_size,
                              hipStream_t stream)
{
  const void* xraw = d_in[0];
  const int* nbr0 = (const int*)d_in[1];
  const int* nbr1 = (const int*)d_in[2];
  const int* nbr2 = (const int*)d_in[3];
  const int* nbr3 = (const int*)d_in[4];
  const int* nbr4 = (const int*)d_in[5];
  const int* d1 = (const int*)d_in[6];
  const int* d2 = (const int*)d_in[7];
  const int* d3 = (const int*)d_in[8];
  const int* d4 = (const int*)d_in[9];
  const int* u1p = (const int*)d_in[10]; const int* u1o = (const int*)d_in[11];
  const int* u2p = (const int*)d_in[12]; const int* u2o = (const int*)d_in[13];
  const int* u3p = (const int*)d_in[14]; const int* u3o = (const int*)d_in[15];
  const int* u4p = (const int*)d_in[16]; const int* u4o = (const int*)d_in[17];
  const void* params = d_in[18];
  (void)in_sizes; (void)n_in;

  static PrepD h_table[64];
  long totalC = 0, totalE = 0;
  int NL = build_table(h_table, &totalC, &totalE);

  char* base = (char*)d_ws; size_t off = 0;
  auto ab = [&](size_t bytes) -> void* { void* p = base + off; off += (bytes + 63) & ~(size_t)63; return p; };
  int* flagp = (int*)ab(64);
  float* st = (float*)ab((size_t)64 * 768 * 4);
  float* Bstf = (float*)ab((size_t)512 * 4);
  float* x0 = (float*)ab((size_t)NP0 * 32 * 4);
  float* x1 = (float*)ab((size_t)NP1 * 32 * 4);
  float* x2 = (float*)ab((size_t)NP2 * 64 * 4);
  float* x3 = (float*)ab((size_t)NP3 * 128 * 4);
  float* x4 = (float*)ab((size_t)NP4 * 256 * 4);
  float* U  = (float*)ab((size_t)NP0 * 96 * 4);
  float* A  = (float*)ab((size_t)NP0 * 96 * 4);
  float* B  = (float*)ab((size_t)NP0 * 128 * 4);
  float* Xp = B;

  size_t wall_bytes = (size_t)totalE * 4;
  size_t rem = (ws_size > off) ? (ws_size - off) : 0;
  bool bigprep = rem >= wall_bytes + 8192;
  u16* Wall = nullptr; PrepD* d_table = nullptr; u16* Wst = nullptr;
  if (bigprep) {
    Wall = (u16*)ab(wall_bytes);
    d_table = (PrepD*)ab(4096);
  } else {
    Wst = (u16*)ab((size_t)5400000 * 2);
  }
  if (off > ws_size) { hipMemsetAsync(d_out, 0, (size_t)out_size * 2, stream); return; }

  long po = 0;
  int bnc = 0;
  int wli = 0;

  auto prepF = [&](int hf, int K, int CI, int CO, int CB32, int NT16) -> long {
    long chunks = (long)K * CB32 * NT16 * 64;
    long halfel = chunks * 8;
    int nb = (int)((chunks + 255) / 256); if (nb > 4096) nb = 4096; if (nb < 1) nb = 1;
    k_prep_frag<<<nb, 256, 0, stream>>>(params, flagp, Wst, po, halfel, hf, K, CI, CO, CB32, NT16);
    po += (long)K * CI * CO;
    return halfel;
  };
  auto getW = [&](int hf, int K, int CI, int CO, int CB32, int NT16, const u16** Wp, long* he) {
    if (bigprep) {
      *Wp = Wall + h_table[wli].dst; *he = totalE;
      ++wli; po += (long)K * CI * CO;
    } else {
      *he = prepF(hf, K, CI, CO, CB32, NT16); *Wp = Wst;
    }
  };
  auto convop = [&](int hf, const void* X, const int* nb_, int K, int CI, int CO, float* Y, int N, int XS) {
    int CB32 = cdiv(CI, 32), NT16 = cdiv(CO, 16);
    const u16* Wp; long he;
    getW(hf, K, CI, CO, CB32, NT16, &Wp, &he);
    launch_conv(stream, cdiv(N, 128), X, nb_, Wp, he, Y, nullptr, 0, flagp, hf, N, K, CB32, NT16, CO, XS, nullptr);
  };
  auto linop = [&](int hf, const void* X, int CI, int CO, float* Y, int N, bool bias, int relu, u16* d16) {
    int CB32 = cdiv(CI, 32), NT16 = cdiv(CO, 16);
    const u16* Wp; long he;
    getW(hf, 1, CI, CO, CB32, NT16, &Wp, &he);
    const float* bp = nullptr;
    if (bias) {
      k_prep_bias<<<cdiv(CO, 256), 256, 0, stream>>>(params, flagp, Bstf, po, CO);
      po += CO; bp = Bstf;
    }
    launch_conv(stream, cdiv(N, 128), X, nullptr, Wp, he, Y, bp, relu, flagp, hf, N, 1, CB32, NT16, CO, CI, d16);
  };
  auto deconvop = [&](const void* X, int xmode, const int* par, const int* ofv, int CI, int CO, float* Y, int N) {
    long wofs = po; po += (long)8 * CI * CO;
    dim3 g(cdiv(CO, 64), cdiv(N, 4));
    k_deconv<<<g, 256, 0, stream>>>(X, par, ofv, params, wofs, flagp, Y, xmode, N, CI, CO);
  };
  auto bnop = [&](const float* X, int N, int C, const void* addp, int addmode, int relu,
                  void* out, int outmode) {
    float* slot = st + (size_t)(bnc++) * 768;
    int total = N * C;
    int total4 = total >> 2;
    int nb1 = cdiv(total4, 4096); if (nb1 > 504) nb1 = 504; if (nb1 < 3) nb1 = 3;
    nb1 = ((nb1 + 2) / 3) * 3;
    k_bn_stats<<<nb1, 256, 0, stream>>>(X, slot, total, C);
    int nb2 = cdiv(total4, 2048); if (nb2 > 510) nb2 = 510; if (nb2 < 3) nb2 = 3;
    nb2 = ((nb2 + 2) / 3) * 3;
    k_bn_apply<<<nb2, 256, 0, stream>>>(X, slot, addp, addmode, out ? out : (void*)X, outmode,
                                        relu, total, C, 1.0f / (float)N);
  };
  auto copyop = [&](const void* S, int smode, u16* D, int N, int Cs, int Cd, int o2) {
    int total4 = (N * Cs) >> 2;
    int nb3 = cdiv(total4, 1024); if (nb3 > 1024) nb3 = 1024; if (nb3 < 1) nb3 = 1;
    k_copycols<<<nb3, 256, 0, stream>>>(S, D, smode, N, Cs, Cd, o2);
  };
  auto storeop = [&](const float* S, size_t eo, int n) {
    int nb4 = cdiv(n >> 2, 1024); if (nb4 > 1024) nb4 = 1024; if (nb4 < 1) nb4 = 1;
    k_store_dyn<<<nb4, 256, 0, stream>>>(S, d_out, flagp, eo, n);
  };
  auto resblock = [&](const int* nb, int N, int CI, int CO,
                      float* H, float* t1, float* t2, float* OUT) {
    convop(0, H, nb, 27, CI, CO, t1, N, CI);
    bnop(t1, N, CO, nullptr, 0, 1, nullptr, 0);
    convop(0, t1, nb, 27, CO, CO, t2, N, CO);
    const float* S;
    if (CI == CO) S = H;
    else { linop(0, H, CI, CO, t1, N, false, 0, nullptr); bnop(t1, N, CO, nullptr, 0, 0, nullptr, 0); S = t1; }
    bnop(t2, N, CO, S, 1, 1, OUT, 0);
  };
  // decoder resblock (fp16): all second-use cases have CI==CO (no alias hazard)
  auto resblock16 = [&](const int* nb, int N, int CI, int CO,
                        u16* H16, float* t1, float* t2, u16* OUT16) {
    convop(1, H16, nb, 27, CI, CO, t1, N, CI);
    bnop(t1, N, CO, nullptr, 0, 1, (u16*)t2, 1);
    convop(1, (u16*)t2, nb, 27, CO, CO, t1, N, CO);
    if (CI == CO) {
      bnop(t1, N, CO, H16, 2, 1, OUT16, 1);
    } else {
      linop(1, H16, CI, CO, t2, N, false, 0, nullptr);
      bnop(t2, N, CO, nullptr, 0, 0, OUT16, 1);       // shortcut S16 -> OUT16 (H dead)
      bnop(t1, N, CO, OUT16, 2, 1, OUT16, 1);         // element-aligned alias: safe
    }
  };

  k_sniff<<<1, 256, 0, stream>>>(xraw, flagp);
  if (bigprep) {
    hipMemcpyAsync(d_table, h_table, (size_t)NL * sizeof(PrepD), hipMemcpyHostToDevice, stream);
    int nbp = (int)((totalC + 255) / 256); if (nbp > 4096) nbp = 4096;
    k_prep_all<<<nbp, 256, 0, stream>>>(params, flagp, Wall, d_table, NL, totalC, totalE);
  }
  hipMemsetAsync(st, 0, (size_t)64 * 768 * 4, stream);
  k_pad<<<1024, 256, 0, stream>>>(xraw, flagp, Xp, NP0);

  // encoder (fp32)
  convop(0, Xp, nbr0, 27, 4, 32, A, NP0, 32);  bnop(A, NP0, 32, nullptr, 0, 1, nullptr, 0);
  convop(0, A, nbr0, 27, 32, 32, x0, NP0, 32); bnop(x0, NP0, 32, nullptr, 0, 1, nullptr, 0);
  convop(0, x0, d1, 8, 32, 32, U, NP1, 32); bnop(U, NP1, 32, nullptr, 0, 1, nullptr, 0);
  resblock(nbr1, NP1, 32, 32, U, A, B, U);
  resblock(nbr1, NP1, 32, 32, U, A, B, x1);
  convop(0, x1, d2, 8, 32, 32, U, NP2, 32); bnop(U, NP2, 32, nullptr, 0, 1, nullptr, 0);
  resblock(nbr2, NP2, 32, 64, U, A, B, U);
  resblock(nbr2, NP2, 64, 64, U, A, B, x2);
  convop(0, x2, d3, 8, 64, 64, U, NP3, 64); bnop(U, NP3, 64, nullptr, 0, 1, nullptr, 0);
  resblock(nbr3, NP3, 64, 128, U, A, B, U);
  resblock(nbr3, NP3, 128, 128, U, A, B, x3);
  convop(0, x3, d4, 8, 128, 128, U, NP4, 128); bnop(U, NP4, 128, nullptr, 0, 1, nullptr, 0);
  resblock(nbr4, NP4, 128, 256, U, A, B, U);
  resblock(nbr4, NP4, 256, 256, U, A, B, x4);

  // decoder (fp16)
  u16* U16 = (u16*)U; u16* B16 = (u16*)B; u16* A16 = (u16*)A;
  deconvop(x4, 0, u1p, u1o, 256, 256, A, NP3);
  bnop(A, NP3, 256, nullptr, 0, 1, U16, 1);
  copyop(U16, 1, B16, NP3, 256, 384, 0); copyop(x3, 0, B16, NP3, 128, 384, 256);
  resblock16(nbr3, NP3, 384, 256, B16, A, U, B16);
  resblock16(nbr3, NP3, 256, 256, B16, A, U, U16);
  deconvop(U16, 1, u2p, u2o, 256, 128, A, NP2);
  bnop(A, NP2, 128, nullptr, 0, 1, U16, 1);
  copyop(U16, 1, B16, NP2, 128, 192, 0); copyop(x2, 0, B16, NP2, 64, 192, 128);
  resblock16(nbr2, NP2, 192, 128, B16, A, U, B16);
  resblock16(nbr2, NP2, 128, 128, B16, A, U, U16);
  deconvop(U16, 1, u3p, u3o, 128, 96, A, NP1);
  bnop(A, NP1, 96, nullptr, 0, 1, U16, 1);
  copyop(U16, 1, B16, NP1, 96, 128, 0); copyop(x1, 0, B16, NP1, 32, 128, 96);
  resblock16(nbr1, NP1, 128, 96, B16, A, U, B16);
  resblock16(nbr1, NP1, 96, 96, B16, A, U, U16);
  deconvop(U16, 1, u4p, u4o, 96, 96, A, NP0);
  bnop(A, NP0, 96, nullptr, 0, 1, U16, 1);
  copyop(U16, 1, B16, NP0, 96, 128, 0); copyop(x0, 0, B16, NP0, 32, 128, 96);
  resblock16(nbr0, NP0, 128, 96, B16, A, U, B16);
  resblock16(nbr0, NP0, 96, 96, B16, A, U, U16);
  // head
  float* x0f = (float*)x0;
  linop(1, U16, 96, 19, x0f, NP0, true, 0, nullptr);
  linop(1, U16, 96, 96, B, NP0, true, 1, A16);
  linop(1, A16, 96, 128, B, NP0, true, 0, nullptr);
  storeop(x0f, 0, NP0 * 19);
  storeop(B, (size_t)NP0 * 19, NP0 * 128);
}

// Round 11
// 3885.926 us; speedup vs baseline: 1.2537x; 1.0332x over previous
//
#include <hip/hip_runtime.h>
#include <hip/hip_bf16.h>
#include <stdint.h>

typedef __hip_bfloat16 hbf;
typedef unsigned short u16;
typedef __attribute__((ext_vector_type(8))) short bfrag;      // 8 bf16
typedef _Float16 __attribute__((ext_vector_type(8))) hfrag;   // 8 fp16
typedef __attribute__((ext_vector_type(4))) float f4;         // 16x16 accumulator

#define NP0 50000
#define NP1 20000
#define NP2 8000
#define NP3 3200
#define NP4 1300

static inline int cdiv(int a, int b) { return (a + b - 1) / b; }

static __device__ __forceinline__ float u2f(u16 u) { return __uint_as_float(((unsigned)u) << 16); }
static __device__ __forceinline__ u16 f2u(float f) {
  hbf h = __float2bfloat16(f);
  u16 r; __builtin_memcpy(&r, &h, 2); return r;
}
static __device__ __forceinline__ u16 f2h(float f) {
  _Float16 h = (_Float16)f;
  u16 r; __builtin_memcpy(&r, &h, 2); return r;
}
static __device__ __forceinline__ float h2f(u16 u) {
  _Float16 h; __builtin_memcpy(&h, &u, 2); return (float)h;
}
static __device__ __forceinline__ float pload(const void* P, int isbf, size_t i) {
  return isbf ? u2f(((const u16*)P)[i]) : ((const float*)P)[i];
}

// Encoder activations: fp32. Decoder (up1..up4 + head): fp16.
// Weights: encoder bf16 hi/lo planes, decoder fp16 hi/lo planes. On a bf16
// wire both lo planes are exactly zero, so lo passes are skipped.
// Deconv (ks=2 transposed) is lowered to the K=8 gather-GEMM with masked
// indices pointing at a zero row: out[n] = sum_k X[(off[n]==k)?par[n]:ZR]@W[k].

struct PrepD {
  long cpre, src, dst;
  int K, CI, CO, CB32, NT16, hf;
};

__global__ void k_sniff(const void* __restrict__ xraw, int* __restrict__ flagp) {
  __shared__ float smax[256];
  const u16* u = (const u16*)xraw;
  float m = 0.f;
  for (int i = threadIdx.x; i < 2048; i += 256) {
    float v = u2f(u[2 * i]);
    if (isnan(v) || isinf(v)) m = 1e30f; else m = fmaxf(m, fabsf(v));
  }
  smax[threadIdx.x] = m;
  __syncthreads();
  for (int s = 128; s > 0; s >>= 1) {
    if (threadIdx.x < s) smax[threadIdx.x] = fmaxf(smax[threadIdx.x], smax[threadIdx.x + s]);
    __syncthreads();
  }
  if (threadIdx.x == 0) *flagp = (smax[0] < 1e4f) ? 1 : 0;
}

__global__ __launch_bounds__(256) void k_prep_all(
    const void* __restrict__ P, const int* __restrict__ flagp, u16* __restrict__ W,
    const PrepD* __restrict__ T, int NL, long totalC, long totalE)
{
  int f = *flagp;
  int L = 0;
  for (long c = (long)blockIdx.x * 256 + threadIdx.x; c < totalC; c += (long)gridDim.x * 256) {
    while (L + 1 < NL && c >= T[L + 1].cpre) ++L;
    PrepD d = T[L];
    long lc = c - d.cpre;
    int lane = (int)(lc & 63); long t = lc >> 6;
    int nt = (int)(t % d.NT16); t /= d.NT16;
    int cb = (int)(t % d.CB32); int k = (int)(t / d.CB32);
    int co = nt * 16 + (lane & 15);
    int cib = cb * 32 + (lane >> 4) * 8;
    u16 hi[8], lo[8];
#pragma unroll
    for (int j = 0; j < 8; ++j) {
      int ci = cib + j; float v = 0.f;
      if (ci < d.CI && co < d.CO) v = pload(P, f, d.src + ((size_t)k * d.CI + ci) * d.CO + co);
      if (d.hf) { u16 h = f2h(v); hi[j] = h; lo[j] = f2h(v - h2f(h)); }
      else      { u16 h = f2u(v); hi[j] = h; lo[j] = f2u(v - u2f(h)); }
    }
    *(bfrag*)(W + d.dst + lc * 8) = *(const bfrag*)hi;
    *(bfrag*)(W + totalE + d.dst + lc * 8) = *(const bfrag*)lo;
  }
}

__global__ __launch_bounds__(256) void k_prep_frag(
    const void* __restrict__ P, const int* __restrict__ flagp, u16* __restrict__ W,
    long src, long halfel, int hf, int K, int CI, int CO, int CB32, int NT16)
{
  int f = *flagp;
  long total = (long)K * CB32 * NT16 * 64;
  for (long c = (long)blockIdx.x * 256 + threadIdx.x; c < total; c += (long)gridDim.x * 256) {
    int lane = (int)(c & 63); long t = c >> 6;
    int nt = (int)(t % NT16); t /= NT16;
    int cb = (int)(t % CB32); int k = (int)(t / CB32);
    int co = nt * 16 + (lane & 15);
    int cib = cb * 32 + (lane >> 4) * 8;
    u16 hi[8], lo[8];
#pragma unroll
    for (int j = 0; j < 8; ++j) {
      int ci = cib + j; float v = 0.f;
      if (ci < CI && co < CO) v = pload(P, f, src + ((size_t)k * CI + ci) * CO + co);
      if (hf) { u16 h = f2h(v); hi[j] = h; lo[j] = f2h(v - h2f(h)); }
      else    { u16 h = f2u(v); hi[j] = h; lo[j] = f2u(v - u2f(h)); }
    }
    *(bfrag*)(W + c * 8) = *(const bfrag*)hi;
    *(bfrag*)(W + halfel + c * 8) = *(const bfrag*)lo;
  }
}

__global__ void k_prep_bias(const void* __restrict__ P, const int* __restrict__ flagp,
                            float* __restrict__ B, long src, int n)
{
  int f = *flagp;
  int i = blockIdx.x * 256 + threadIdx.x;
  if (i < n) B[i] = pload(P, f, src + i);
}

__global__ void k_pad(const void* __restrict__ xraw, const int* __restrict__ flagp,
                      float* __restrict__ Xp, int N)
{
  int f = *flagp; int total = N * 32;
  for (int i = blockIdx.x * 256 + threadIdx.x; i < total; i += gridDim.x * 256) {
    int n = i >> 5, cc = i & 31;
    Xp[i] = (cc < 4) ? pload(xraw, f, (size_t)n * 4 + cc) : 0.f;
  }
}

// ---- masked index builder for deconv-as-conv ----
__global__ void k_mk_didx(const int* __restrict__ par, const int* __restrict__ off,
                          int* __restrict__ idx, int N, int ZR)
{
  int stride = gridDim.x * 256;
  for (int i = blockIdx.x * 256 + threadIdx.x; i < N; i += stride) {
    int p = par[i], o = off[i];
#pragma unroll
    for (int k = 0; k < 8; ++k) idx[(size_t)i * 8 + k] = (k == o) ? p : ZR;
  }
}

// ---- MFMA gather-GEMM, reduction-split over gridDim.z ----
template<int NT>
__global__ __launch_bounds__(256) void k_conv_mfma(
    const void* __restrict__ Xv, const int* __restrict__ nbr,
    const u16* __restrict__ Wp, long halfel, float* __restrict__ Y,
    const float* __restrict__ bias, int relu, const int* __restrict__ flagp,
    int ahalf, int N, int K, int CB32, int NT16, int CO, int XS, int tlen, int atomic)
{
  const int f = *flagp;
  const int lane = threadIdx.x & 63;
  const int wv = threadIdx.x >> 6;
  const int rowbase = blockIdx.x * 128 + wv * 32;
  const int ntb = blockIdx.y * NT;
  const int ml = lane & 15;
  const int quad = lane >> 4;
  const int ktot = K * CB32;
  const int t0 = blockIdx.z * tlen;
  const int t1 = (t0 + tlen < ktot) ? (t0 + tlen) : ktot;
  if (t0 >= t1) return;

  f4 acc[2][NT];
#pragma unroll
  for (int i = 0; i < 2; ++i)
#pragma unroll
    for (int j = 0; j < NT; ++j) acc[i][j] = (f4)(0.f);

  int k = t0 / CB32;
  int cb = t0 - k * CB32;
  int idx[2];
  bool fresh = true;

  if (ahalf) {
    const u16* X = (const u16*)Xv;
    if (f) {
      for (int t = t0; t < t1; ++t) {
        if (fresh) {
#pragma unroll
          for (int mt = 0; mt < 2; ++mt) {
            int r = rowbase + mt * 16 + ml;
            idx[mt] = (r < N) ? (nbr ? nbr[(size_t)r * K + k] : r) : 0;
          }
          fresh = false;
        }
        const u16* WH = Wp + (size_t)t * NT16 * 512;
        hfrag bh[NT];
#pragma unroll
        for (int nt = 0; nt < NT; ++nt)
          bh[nt] = *(const hfrag*)(WH + ((size_t)(ntb + nt) * 64 + lane) * 8);
        hfrag a[2];
#pragma unroll
        for (int mt = 0; mt < 2; ++mt)
          a[mt] = *(const hfrag*)(X + (size_t)idx[mt] * XS + cb * 32 + quad * 8);
#pragma unroll
        for (int mt = 0; mt < 2; ++mt)
#pragma unroll
          for (int nt = 0; nt < NT; ++nt)
            acc[mt][nt] = __builtin_amdgcn_mfma_f32_16x16x32_f16(a[mt], bh[nt], acc[mt][nt], 0, 0, 0);
        if (++cb == CB32) { cb = 0; ++k; fresh = true; }
      }
    } else {
      for (int t = t0; t < t1; ++t) {
        if (fresh) {
#pragma unroll
          for (int mt = 0; mt < 2; ++mt) {
            int r = rowbase + mt * 16 + ml;
            idx[mt] = (r < N) ? (nbr ? nbr[(size_t)r * K + k] : r) : 0;
          }
          fresh = false;
        }
        const u16* WH = Wp + (size_t)t * NT16 * 512;
        const u16* WL = WH + halfel;
        hfrag bh[NT], bl[NT];
#pragma unroll
        for (int nt = 0; nt < NT; ++nt) {
          size_t o = ((size_t)(ntb + nt) * 64 + lane) * 8;
          bh[nt] = *(const hfrag*)(WH + o);
          bl[nt] = *(const hfrag*)(WL + o);
        }
        hfrag a[2];
#pragma unroll
        for (int mt = 0; mt < 2; ++mt)
          a[mt] = *(const hfrag*)(X + (size_t)idx[mt] * XS + cb * 32 + quad * 8);
#pragma unroll
        for (int mt = 0; mt < 2; ++mt)
#pragma unroll
          for (int nt = 0; nt < NT; ++nt) {
            acc[mt][nt] = __builtin_amdgcn_mfma_f32_16x16x32_f16(a[mt], bl[nt], acc[mt][nt], 0, 0, 0);
            acc[mt][nt] = __builtin_amdgcn_mfma_f32_16x16x32_f16(a[mt], bh[nt], acc[mt][nt], 0, 0, 0);
          }
        if (++cb == CB32) { cb = 0; ++k; fresh = true; }
      }
    }
  } else {
    const float* X = (const float*)Xv;
    if (f) {
      for (int t = t0; t < t1; ++t) {
        if (fresh) {
#pragma unroll
          for (int mt = 0; mt < 2; ++mt) {
            int r = rowbase + mt * 16 + ml;
            idx[mt] = (r < N) ? (nbr ? nbr[(size_t)r * K + k] : r) : 0;
          }
          fresh = false;
        }
        const u16* WH = Wp + (size_t)t * NT16 * 512;
        bfrag bh[NT];
#pragma unroll
        for (int nt = 0; nt < NT; ++nt)
          bh[nt] = *(const bfrag*)(WH + ((size_t)(ntb + nt) * 64 + lane) * 8);
        bfrag ahi[2], alo[2];
#pragma unroll
        for (int mt = 0; mt < 2; ++mt) {
          const float* ap = X + (size_t)idx[mt] * XS + cb * 32 + quad * 8;
          float4 q0 = *(const float4*)ap;
          float4 q1 = *(const float4*)(ap + 4);
          float av[8] = {q0.x, q0.y, q0.z, q0.w, q1.x, q1.y, q1.z, q1.w};
          u16 hi8[8], lo8[8];
#pragma unroll
          for (int j = 0; j < 8; ++j) {
            u16 hh = f2u(av[j]);
            hi8[j] = hh;
            lo8[j] = f2u(av[j] - u2f(hh));
          }
          __builtin_memcpy(&ahi[mt], hi8, 16);
          __builtin_memcpy(&alo[mt], lo8, 16);
        }
#pragma unroll
        for (int mt = 0; mt < 2; ++mt)
#pragma unroll
          for (int nt = 0; nt < NT; ++nt) {
            acc[mt][nt] = __builtin_amdgcn_mfma_f32_16x16x32_bf16(alo[mt], bh[nt], acc[mt][nt], 0, 0, 0);
            acc[mt][nt] = __builtin_amdgcn_mfma_f32_16x16x32_bf16(ahi[mt], bh[nt], acc[mt][nt], 0, 0, 0);
          }
        if (++cb == CB32) { cb = 0; ++k; fresh = true; }
      }
    } else {
      for (int t = t0; t < t1; ++t) {
        if (fresh) {
#pragma unroll
          for (int mt = 0; mt < 2; ++mt) {
            int r = rowbase + mt * 16 + ml;
            idx[mt] = (r < N) ? (nbr ? nbr[(size_t)r * K + k] : r) : 0;
          }
          fresh = false;
        }
        const u16* WH = Wp + (size_t)t * NT16 * 512;
        const u16* WL = WH + halfel;
        bfrag bh[NT], bl[NT];
#pragma unroll
        for (int nt = 0; nt < NT; ++nt) {
          size_t o = ((size_t)(ntb + nt) * 64 + lane) * 8;
          bh[nt] = *(const bfrag*)(WH + o);
          bl[nt] = *(const bfrag*)(WL + o);
        }
        bfrag ahi[2], alo[2];
#pragma unroll
        for (int mt = 0; mt < 2; ++mt) {
          const float* ap = X + (size_t)idx[mt] * XS + cb * 32 + quad * 8;
          float4 q0 = *(const float4*)ap;
          float4 q1 = *(const float4*)(ap + 4);
          float av[8] = {q0.x, q0.y, q0.z, q0.w, q1.x, q1.y, q1.z, q1.w};
          u16 hi8[8], lo8[8];
#pragma unroll
          for (int j = 0; j < 8; ++j) {
            u16 hh = f2u(av[j]);
            hi8[j] = hh;
            lo8[j] = f2u(av[j] - u2f(hh));
          }
          __builtin_memcpy(&ahi[mt], hi8, 16);
          __builtin_memcpy(&alo[mt], lo8, 16);
        }
#pragma unroll
        for (int mt = 0; mt < 2; ++mt)
#pragma unroll
          for (int nt = 0; nt < NT; ++nt) {
            acc[mt][nt] = __builtin_amdgcn_mfma_f32_16x16x32_bf16(alo[mt], bh[nt], acc[mt][nt], 0, 0, 0);
            acc[mt][nt] = __builtin_amdgcn_mfma_f32_16x16x32_bf16(ahi[mt], bl[nt], acc[mt][nt], 0, 0, 0);
            acc[mt][nt] = __builtin_amdgcn_mfma_f32_16x16x32_bf16(ahi[mt], bh[nt], acc[mt][nt], 0, 0, 0);
          }
        if (++cb == CB32) { cb = 0; ++k; fresh = true; }
      }
    }
  }

#pragma unroll
  for (int mt = 0; mt < 2; ++mt) {
#pragma unroll
    for (int nt = 0; nt < NT; ++nt) {
      int col = (ntb + nt) * 16 + ml;
      if (col >= CO) continue;
      float bvv = bias ? bias[col] : 0.f;
#pragma unroll
      for (int reg = 0; reg < 4; ++reg) {
        int row = rowbase + mt * 16 + quad * 4 + reg;
        if (row < N) {
          if (atomic) {
            atomicAdd(&Y[(size_t)row * CO + col], acc[mt][nt][reg]);
          } else {
            float v = acc[mt][nt][reg] + bvv;
            if (relu) v = fmaxf(v, 0.f);
            Y[(size_t)row * CO + col] = v;
          }
        }
      }
    }
  }
}

__global__ void k_bias_relu(float* __restrict__ Y, const float* __restrict__ bias,
                            u16* __restrict__ d16, int relu, int total, int CO)
{
  int stride = gridDim.x * 256;
  for (int i = blockIdx.x * 256 + threadIdx.x; i < total; i += stride) {
    int c = i % CO;
    float v = Y[i] + (bias ? bias[c] : 0.f);
    if (relu) v = fmaxf(v, 0.f);
    Y[i] = v;
    if (d16) d16[i] = f2h(v);
  }
}

static void launch_conv(hipStream_t s, int bx, const void* X, const int* nbr,
                        const u16* W, long halfel, float* Y, const float* bias, int relu,
                        const int* flagp, int ahalf, int N, int K, int CB32, int NT16, int CO, int XS,
                        u16* d16)
{
  int NT = (NT16 % 6 == 0) ? 6 : ((NT16 % 4 == 0) ? 4 : 2);
  int ny = NT16 / NT;
  int ktot = K * CB32;
  long blocks = (long)bx * ny;
  int ZS = 1;
  if (ktot > 1) {
    ZS = (int)((1024 + blocks - 1) / blocks);
    if (ZS > ktot) ZS = ktot;
    if (ZS < 1) ZS = 1;
  }
  int tlen = cdiv(ktot, ZS);
  ZS = cdiv(ktot, tlen);
  int atomic = (ZS > 1) ? 1 : 0;
  if (atomic) hipMemsetAsync(Y, 0, (size_t)N * CO * 4, s);
  dim3 g(bx, ny, ZS);
  if (NT == 6)      k_conv_mfma<6><<<g, 256, 0, s>>>(X, nbr, W, halfel, Y, bias, relu, flagp, ahalf, N, K, CB32, NT16, CO, XS, tlen, atomic);
  else if (NT == 4) k_conv_mfma<4><<<g, 256, 0, s>>>(X, nbr, W, halfel, Y, bias, relu, flagp, ahalf, N, K, CB32, NT16, CO, XS, tlen, atomic);
  else              k_conv_mfma<2><<<g, 256, 0, s>>>(X, nbr, W, halfel, Y, bias, relu, flagp, ahalf, N, K, CB32, NT16, CO, XS, tlen, atomic);
  if ((atomic && (bias || relu)) || d16) {
    int total = N * CO;
    int nb = cdiv(total, 1024); if (nb > 1024) nb = 1024; if (nb < 1) nb = 1;
    k_bias_relu<<<nb, 256, 0, s>>>(Y, atomic ? bias : nullptr, d16, atomic ? relu : 0, total, CO);
  }
}

__global__ __launch_bounds__(256) void k_bn_stats(
    const float* __restrict__ X, float* __restrict__ st, int total, int C)
{
  __shared__ float ssum[384], ssq[384];
  for (int c = threadIdx.x; c < C; c += 256) { ssum[c] = 0.f; ssq[c] = 0.f; }
  __syncthreads();
  int gid = blockIdx.x * 256 + threadIdx.x;
  int total4 = total >> 2;
  int stride = gridDim.x * 256;
  int c0 = (gid * 4) % C;
  float s0 = 0.f, s1 = 0.f, s2 = 0.f, s3 = 0.f;
  float q0 = 0.f, q1 = 0.f, q2 = 0.f, q3 = 0.f;
  for (int i = gid; i < total4; i += stride) {
    float4 v = ((const float4*)X)[i];
    s0 += v.x; q0 += v.x * v.x;
    s1 += v.y; q1 += v.y * v.y;
    s2 += v.z; q2 += v.z * v.z;
    s3 += v.w; q3 += v.w * v.w;
  }
  atomicAdd(&ssum[c0], s0);     atomicAdd(&ssq[c0], q0);
  atomicAdd(&ssum[c0 + 1], s1); atomicAdd(&ssq[c0 + 1], q1);
  atomicAdd(&ssum[c0 + 2], s2); atomicAdd(&ssq[c0 + 2], q2);
  atomicAdd(&ssum[c0 + 3], s3); atomicAdd(&ssq[c0 + 3], q3);
  __syncthreads();
  for (int c = threadIdx.x; c < C; c += 256) {
    atomicAdd(&st[c], ssum[c]); atomicAdd(&st[384 + c], ssq[c]);
  }
}

__global__ __launch_bounds__(256) void k_bn_apply(
    const float* __restrict__ X, const float* __restrict__ st,
    const void* __restrict__ addp, int addmode,
    void* __restrict__ Yo, int outmode, int relu, int total, int C, float invN)
{
  __shared__ float mean[384], rsig[384];
  for (int c = threadIdx.x; c < C; c += 256) {
    float mm = st[c] * invN;
    float vv = st[384 + c] * invN - mm * mm;
    mean[c] = mm; rsig[c] = rsqrtf(vv + 1e-5f);
  }
  __syncthreads();
  int gid = blockIdx.x * 256 + threadIdx.x;
  int total4 = total >> 2;
  int stride = gridDim.x * 256;
  int c0 = (gid * 4) % C;
  float m0 = mean[c0], m1 = mean[c0 + 1], m2 = mean[c0 + 2], m3 = mean[c0 + 3];
  float r0 = rsig[c0], r1 = rsig[c0 + 1], r2 = rsig[c0 + 2], r3 = rsig[c0 + 3];
  for (int i = gid; i < total4; i += stride) {
    float4 v = ((const float4*)X)[i];
    float w0 = (v.x - m0) * r0, w1 = (v.y - m1) * r1;
    float w2 = (v.z - m2) * r2, w3 = (v.w - m3) * r3;
    if (addmode == 1) {
      float4 a = ((const float4*)addp)[i];
      w0 += a.x; w1 += a.y; w2 += a.z; w3 += a.w;
    } else if (addmode == 2) {
      ushort4 ah = *(const ushort4*)((const u16*)addp + (size_t)i * 4);
      w0 += h2f(ah.x); w1 += h2f(ah.y); w2 += h2f(ah.z); w3 += h2f(ah.w);
    }
    if (relu) {
      w0 = fmaxf(w0, 0.f); w1 = fmaxf(w1, 0.f);
      w2 = fmaxf(w2, 0.f); w3 = fmaxf(w3, 0.f);
    }
    if (outmode == 0) {
      float4 o; o.x = w0; o.y = w1; o.z = w2; o.w = w3;
      ((float4*)Yo)[i] = o;
    } else {
      ushort4 hh; hh.x = f2h(w0); hh.y = f2h(w1); hh.z = f2h(w2); hh.w = f2h(w3);
      *(ushort4*)((u16*)Yo + (size_t)i * 4) = hh;
    }
  }
}

__global__ void k_copycols(const void* __restrict__ Sv, u16* __restrict__ D,
                           int smode, int N, int Cs, int Cd, int off)
{
  int csq = Cs >> 2;
  int total4 = N * csq;
  int stride = gridDim.x * 256;
  for (int i = blockIdx.x * 256 + threadIdx.x; i < total4; i += stride) {
    int n = i / csq, cc = (i - n * csq) * 4;
    ushort4 hh;
    if (smode == 0) {
      float4 v = ((const float4*)Sv)[i];
      hh.x = f2h(v.x); hh.y = f2h(v.y); hh.z = f2h(v.z); hh.w = f2h(v.w);
    } else {
      hh = *(const ushort4*)((const u16*)Sv + (size_t)i * 4);
    }
    *(ushort4*)(D + (size_t)n * Cd + off + cc) = hh;
  }
}

__global__ void k_store_dyn(const float* __restrict__ S, void* __restrict__ D,
                            const int* __restrict__ flagp, size_t eofs, int n)
{
  int f = *flagp;
  int n4 = n >> 2;
  int stride = gridDim.x * 256;
  for (int i = blockIdx.x * 256 + threadIdx.x; i < n4; i += stride) {
    float4 v = ((const float4*)S)[i];
    if (f) {
      ushort4 u;
      u.x = f2u(v.x); u.y = f2u(v.y); u.z = f2u(v.z); u.w = f2u(v.w);
      *(ushort4*)((u16*)D + eofs + (size_t)i * 4) = u;
    } else {
      *(float4*)((float*)D + eofs + (size_t)i * 4) = v;
    }
  }
}

static int build_table(PrepD* T, long* totalC, long* totalE) {
  int n = 0; long po = 0, ce = 0, cc = 0;
  auto W = [&](int K, int CI, int CO, int hf) {
    int CB = cdiv(CI, 32), NTx = cdiv(CO, 16);
    long ch = (long)K * CB * NTx * 64;
    T[n].cpre = cc; T[n].src = po; T[n].dst = ce;
    T[n].K = K; T[n].CI = CI; T[n].CO = CO; T[n].CB32 = CB; T[n].NT16 = NTx; T[n].hf = hf;
    ++n; cc += ch; ce += ch * 8; po += (long)K * CI * CO;
  };
  auto SKIP = [&](long e) { po += e; };
  W(27, 4, 32, 0); W(27, 32, 32, 0);
  W(8, 32, 32, 0); W(27, 32, 32, 0); W(27, 32, 32, 0); W(27, 32, 32, 0); W(27, 32, 32, 0);
  W(8, 32, 32, 0); W(27, 32, 64, 0); W(27, 64, 64, 0); W(1, 32, 64, 0); W(27, 64, 64, 0); W(27, 64, 64, 0);
  W(8, 64, 64, 0); W(27, 64, 128, 0); W(27, 128, 128, 0); W(1, 64, 128, 0); W(27, 128, 128, 0); W(27, 128, 128, 0);
  W(8, 128, 128, 0); W(27, 128, 256, 0); W(27, 256, 256, 0); W(1, 128, 256, 0); W(27, 256, 256, 0); W(27, 256, 256, 0);
  W(8, 256, 256, 0);   // up1 deconv (A = x4 fp32 -> bf16 weights)
  W(27, 384, 256, 1); W(27, 256, 256, 1); W(1, 384, 256, 1); W(27, 256, 256, 1); W(27, 256, 256, 1);
  W(8, 256, 128, 1);   // up2 deconv (A fp16)
  W(27, 192, 128, 1); W(27, 128, 128, 1); W(1, 192, 128, 1); W(27, 128, 128, 1); W(27, 128, 128, 1);
  W(8, 128, 96, 1);    // up3 deconv
  W(27, 128, 96, 1); W(27, 96, 96, 1); W(1, 128, 96, 1); W(27, 96, 96, 1); W(27, 96, 96, 1);
  W(8, 96, 96, 1);     // up4 deconv
  W(27, 128, 96, 1); W(27, 96, 96, 1); W(1, 128, 96, 1); W(27, 96, 96, 1); W(27, 96, 96, 1);
  W(1, 96, 19, 1); SKIP(19); W(1, 96, 96, 1); SKIP(96); W(1, 96, 128, 1); SKIP(128);
  *totalC = cc; *totalE = ce;
  return n;
}

extern "C" void kernel_launch(void* const* d_in, const int* in_sizes, int n_in,
                              void* d_out, int out_size, void* d_ws, size_t ws_size,
                              hipStream_t stream)
{
  const void* xraw = d_in[0];
  const int* nbr0 = (const int*)d_in[1];
  const int* nbr1 = (const int*)d_in[2];
  const int* nbr2 = (const int*)d_in[3];
  const int* nbr3 = (const int*)d_in[4];
  const int* nbr4 = (const int*)d_in[5];
  const int* d1 = (const int*)d_in[6];
  const int* d2 = (const int*)d_in[7];
  const int* d3 = (const int*)d_in[8];
  const int* d4 = (const int*)d_in[9];
  const int* u1p = (const int*)d_in[10]; const int* u1o = (const int*)d_in[11];
  const int* u2p = (const int*)d_in[12]; const int* u2o = (const int*)d_in[13];
  const int* u3p = (const int*)d_in[14]; const int* u3o = (const int*)d_in[15];
  const int* u4p = (const int*)d_in[16]; const int* u4o = (const int*)d_in[17];
  const void* params = d_in[18];
  (void)in_sizes; (void)n_in;

  static PrepD h_table[64];
  long totalC = 0, totalE = 0;
  int NL = build_table(h_table, &totalC, &totalE);

  char* base = (char*)d_ws; size_t off = 0;
  auto ab = [&](size_t bytes) -> void* { void* p = base + off; off += (bytes + 63) & ~(size_t)63; return p; };
  int* flagp = (int*)ab(64);
  float* st = (float*)ab((size_t)64 * 768 * 4);
  float* Bstf = (float*)ab((size_t)512 * 4);
  int* didx = (int*)ab((size_t)NP0 * 8 * 4);              // deconv masked indices
  float* x0 = (float*)ab((size_t)NP0 * 32 * 4);
  float* x1 = (float*)ab((size_t)NP1 * 32 * 4);
  float* x2 = (float*)ab((size_t)NP2 * 64 * 4);
  float* x3 = (float*)ab((size_t)NP3 * 128 * 4);
  float* x4 = (float*)ab((size_t)(NP4 + 1) * 256 * 4);    // +1 zero row for deconv
  float* U  = (float*)ab((size_t)NP0 * 96 * 4);
  float* A  = (float*)ab((size_t)NP0 * 96 * 4);
  float* B  = (float*)ab((size_t)NP0 * 128 * 4);
  float* Xp = B;

  size_t wall_bytes = (size_t)totalE * 4;
  size_t rem = (ws_size > off) ? (ws_size - off) : 0;
  bool bigprep = rem >= wall_bytes + 8192;
  u16* Wall = nullptr; PrepD* d_table = nullptr; u16* Wst = nullptr;
  if (bigprep) {
    Wall = (u16*)ab(wall_bytes);
    d_table = (PrepD*)ab(4096);
  } else {
    Wst = (u16*)ab((size_t)5400000 * 2);
  }
  if (off > ws_size) { hipMemsetAsync(d_out, 0, (size_t)out_size * 2, stream); return; }

  long po = 0;
  int bnc = 0;
  int wli = 0;

  auto prepF = [&](int hf, int K, int CI, int CO, int CB32, int NT16) -> long {
    long chunks = (long)K * CB32 * NT16 * 64;
    long halfel = chunks * 8;
    int nb = (int)((chunks + 255) / 256); if (nb > 4096) nb = 4096; if (nb < 1) nb = 1;
    k_prep_frag<<<nb, 256, 0, stream>>>(params, flagp, Wst, po, halfel, hf, K, CI, CO, CB32, NT16);
    po += (long)K * CI * CO;
    return halfel;
  };
  auto getW = [&](int hf, int K, int CI, int CO, int CB32, int NT16, const u16** Wp, long* he) {
    if (bigprep) {
      *Wp = Wall + h_table[wli].dst; *he = totalE;
      ++wli; po += (long)K * CI * CO;
    } else {
      *he = prepF(hf, K, CI, CO, CB32, NT16); *Wp = Wst;
    }
  };
  auto convop = [&](int hf, const void* X, const int* nb_, int K, int CI, int CO, float* Y, int N, int XS) {
    int CB32 = cdiv(CI, 32), NT16 = cdiv(CO, 16);
    const u16* Wp; long he;
    getW(hf, K, CI, CO, CB32, NT16, &Wp, &he);
    launch_conv(stream, cdiv(N, 128), X, nb_, Wp, he, Y, nullptr, 0, flagp, hf, N, K, CB32, NT16, CO, XS, nullptr);
  };
  auto linop = [&](int hf, const void* X, int CI, int CO, float* Y, int N, bool bias, int relu, u16* d16) {
    int CB32 = cdiv(CI, 32), NT16 = cdiv(CO, 16);
    const u16* Wp; long he;
    getW(hf, 1, CI, CO, CB32, NT16, &Wp, &he);
    const float* bp = nullptr;
    if (bias) {
      k_prep_bias<<<cdiv(CO, 256), 256, 0, stream>>>(params, flagp, Bstf, po, CO);
      po += CO; bp = Bstf;
    }
    launch_conv(stream, cdiv(N, 128), X, nullptr, Wp, he, Y, bp, relu, flagp, hf, N, 1, CB32, NT16, CO, CI, d16);
  };
  // deconv as masked K=8 gather-GEMM; X has a zero row at index Ns
  auto deconvop = [&](int hf, const void* X, int Ns, const int* par, const int* ofv,
                      int CI, int CO, float* Y, int N) {
    if (hf) hipMemsetAsync((u16*)X + (size_t)Ns * CI, 0, (size_t)CI * 2, stream);
    else    hipMemsetAsync((float*)X + (size_t)Ns * CI, 0, (size_t)CI * 4, stream);
    int nbl = cdiv(N, 256); if (nbl > 1024) nbl = 1024; if (nbl < 1) nbl = 1;
    k_mk_didx<<<nbl, 256, 0, stream>>>(par, ofv, didx, N, Ns);
    convop(hf, X, didx, 8, CI, CO, Y, N, CI);
  };
  auto bnop = [&](const float* X, int N, int C, const void* addp, int addmode, int relu,
                  void* out, int outmode) {
    float* slot = st + (size_t)(bnc++) * 768;
    int total = N * C;
    int total4 = total >> 2;
    int nb1 = cdiv(total4, 4096); if (nb1 > 504) nb1 = 504; if (nb1 < 3) nb1 = 3;
    nb1 = ((nb1 + 2) / 3) * 3;
    k_bn_stats<<<nb1, 256, 0, stream>>>(X, slot, total, C);
    int nb2 = cdiv(total4, 2048); if (nb2 > 510) nb2 = 510; if (nb2 < 3) nb2 = 3;
    nb2 = ((nb2 + 2) / 3) * 3;
    k_bn_apply<<<nb2, 256, 0, stream>>>(X, slot, addp, addmode, out ? out : (void*)X, outmode,
                                        relu, total, C, 1.0f / (float)N);
  };
  auto copyop = [&](const void* S, int smode, u16* D, int N, int Cs, int Cd, int o2) {
    int total4 = (N * Cs) >> 2;
    int nb3 = cdiv(total4, 1024); if (nb3 > 1024) nb3 = 1024; if (nb3 < 1) nb3 = 1;
    k_copycols<<<nb3, 256, 0, stream>>>(S, D, smode, N, Cs, Cd, o2);
  };
  auto storeop = [&](const float* S, size_t eo, int n) {
    int nb4 = cdiv(n >> 2, 1024); if (nb4 > 1024) nb4 = 1024; if (nb4 < 1) nb4 = 1;
    k_store_dyn<<<nb4, 256, 0, stream>>>(S, d_out, flagp, eo, n);
  };
  auto resblock = [&](const int* nb, int N, int CI, int CO,
                      float* H, float* t1, float* t2, float* OUT) {
    convop(0, H, nb, 27, CI, CO, t1, N, CI);
    bnop(t1, N, CO, nullptr, 0, 1, nullptr, 0);
    convop(0, t1, nb, 27, CO, CO, t2, N, CO);
    const float* S;
    if (CI == CO) S = H;
    else { linop(0, H, CI, CO, t1, N, false, 0, nullptr); bnop(t1, N, CO, nullptr, 0, 0, nullptr, 0); S = t1; }
    bnop(t2, N, CO, S, 1, 1, OUT, 0);
  };
  auto resblock16 = [&](const int* nb, int N, int CI, int CO,
                        u16* H16, float* t1, float* t2, u16* OUT16) {
    convop(1, H16, nb, 27, CI, CO, t1, N, CI);
    bnop(t1, N, CO, nullptr, 0, 1, (u16*)t2, 1);
    convop(1, (u16*)t2, nb, 27, CO, CO, t1, N, CO);
    if (CI == CO) {
      bnop(t1, N, CO, H16, 2, 1, OUT16, 1);
    } else {
      linop(1, H16, CI, CO, t2, N, false, 0, nullptr);
      bnop(t2, N, CO, nullptr, 0, 0, OUT16, 1);
      bnop(t1, N, CO, OUT16, 2, 1, OUT16, 1);
    }
  };

  k_sniff<<<1, 256, 0, stream>>>(xraw, flagp);
  if (bigprep) {
    hipMemcpyAsync(d_table, h_table, (size_t)NL * sizeof(PrepD), hipMemcpyHostToDevice, stream);
    int nbp = (int)((totalC + 255) / 256); if (nbp > 4096) nbp = 4096;
    k_prep_all<<<nbp, 256, 0, stream>>>(params, flagp, Wall, d_table, NL, totalC, totalE);
  }
  hipMemsetAsync(st, 0, (size_t)64 * 768 * 4, stream);
  k_pad<<<1024, 256, 0, stream>>>(xraw, flagp, Xp, NP0);

  // encoder (fp32)
  convop(0, Xp, nbr0, 27, 4, 32, A, NP0, 32);  bnop(A, NP0, 32, nullptr, 0, 1, nullptr, 0);
  convop(0, A, nbr0, 27, 32, 32, x0, NP0, 32); bnop(x0, NP0, 32, nullptr, 0, 1, nullptr, 0);
  convop(0, x0, d1, 8, 32, 32, U, NP1, 32); bnop(U, NP1, 32, nullptr, 0, 1, nullptr, 0);
  resblock(nbr1, NP1, 32, 32, U, A, B, U);
  resblock(nbr1, NP1, 32, 32, U, A, B, x1);
  convop(0, x1, d2, 8, 32, 32, U, NP2, 32); bnop(U, NP2, 32, nullptr, 0, 1, nullptr, 0);
  resblock(nbr2, NP2, 32, 64, U, A, B, U);
  resblock(nbr2, NP2, 64, 64, U, A, B, x2);
  convop(0, x2, d3, 8, 64, 64, U, NP3, 64); bnop(U, NP3, 64, nullptr, 0, 1, nullptr, 0);
  resblock(nbr3, NP3, 64, 128, U, A, B, U);
  resblock(nbr3, NP3, 128, 128, U, A, B, x3);
  convop(0, x3, d4, 8, 128, 128, U, NP4, 128); bnop(U, NP4, 128, nullptr, 0, 1, nullptr, 0);
  resblock(nbr4, NP4, 128, 256, U, A, B, U);
  resblock(nbr4, NP4, 256, 256, U, A, B, x4);

  // decoder (fp16)
  u16* U16 = (u16*)U; u16* B16 = (u16*)B; u16* A16 = (u16*)A;
  deconvop(0, x4, NP4, u1p, u1o, 256, 256, A, NP3);
  bnop(A, NP3, 256, nullptr, 0, 1, U16, 1);
  copyop(U16, 1, B16, NP3, 256, 384, 0); copyop(x3, 0, B16, NP3, 128, 384, 256);
  resblock16(nbr3, NP3, 384, 256, B16, A, U, B16);
  resblock16(nbr3, NP3, 256, 256, B16, A, U, U16);
  deconvop(1, U16, NP3, u2p, u2o, 256, 128, A, NP2);
  bnop(A, NP2, 128, nullptr, 0, 1, U16, 1);
  copyop(U16, 1, B16, NP2, 128, 192, 0); copyop(x2, 0, B16, NP2, 64, 192, 128);
  resblock16(nbr2, NP2, 192, 128, B16, A, U, B16);
  resblock16(nbr2, NP2, 128, 128, B16, A, U, U16);
  deconvop(1, U16, NP2, u3p, u3o, 128, 96, A, NP1);
  bnop(A, NP1, 96, nullptr, 0, 1, U16, 1);
  copyop(U16, 1, B16, NP1, 96, 128, 0); copyop(x1, 0, B16, NP1, 32, 128, 96);
  resblock16(nbr1, NP1, 128, 96, B16, A, U, B16);
  resblock16(nbr1, NP1, 96, 96, B16, A, U, U16);
  deconvop(1, U16, NP1, u4p, u4o, 96, 96, A, NP0);
  bnop(A, NP0, 96, nullptr, 0, 1, U16, 1);
  copyop(U16, 1, B16, NP0, 96, 128, 0); copyop(x0, 0, B16, NP0, 32, 128, 96);
  resblock16(nbr0, NP0, 128, 96, B16, A, U, B16);
  resblock16(nbr0, NP0, 96, 96, B16, A, U, U16);
  // head
  float* x0f = (float*)x0;
  linop(1, U16, 96, 19, x0f, NP0, true, 0, nullptr);
  linop(1, U16, 96, 96, B, NP0, true, 1, A16);
  linop(1, A16, 96, 128, B, NP0, true, 0, nullptr);
  storeop(x0f, 0, NP0 * 19);
  storeop(B, (size_t)NP0 * 19, NP0 * 128);
}

// Round 12
// 3700.784 us; speedup vs baseline: 1.3164x; 1.0500x over previous
//
#include <hip/hip_runtime.h>
#include <hip/hip_bf16.h>
#include <stdint.h>

typedef __hip_bfloat16 hbf;
typedef unsigned short u16;
typedef __attribute__((ext_vector_type(8))) short bfrag;      // 8 bf16
typedef _Float16 __attribute__((ext_vector_type(8))) hfrag;   // 8 fp16
typedef __attribute__((ext_vector_type(4))) float f4;         // 16x16 accumulator

#define NP0 50000
#define NP1 20000
#define NP2 8000
#define NP3 3200
#define NP4 1300

static inline int cdiv(int a, int b) { return (a + b - 1) / b; }

static __device__ __forceinline__ float u2f(u16 u) { return __uint_as_float(((unsigned)u) << 16); }
static __device__ __forceinline__ u16 f2u(float f) {
  hbf h = __float2bfloat16(f);
  u16 r; __builtin_memcpy(&r, &h, 2); return r;
}
static __device__ __forceinline__ u16 f2h(float f) {
  _Float16 h = (_Float16)f;
  u16 r; __builtin_memcpy(&r, &h, 2); return r;
}
static __device__ __forceinline__ float h2f(u16 u) {
  _Float16 h; __builtin_memcpy(&h, &u, 2); return (float)h;
}
static __device__ __forceinline__ float pload(const void* P, int isbf, size_t i) {
  return isbf ? u2f(((const u16*)P)[i]) : ((const float*)P)[i];
}

// ALL activations fp16 (2^-12/layer rounding; R6 proved bf16's 2^-9 fails at
// 0.379, fp16 scales to ~0.047 < 0.068 threshold; decoder-fp16 measured at the
// 0.0156 output floor). Weights: fp16 hi/lo planes; on the bf16 wire the lo
// plane is exactly zero (bf16 is exactly representable in fp16) -> 1 MFMA/pair.
// Deconv lowered to masked K=8 gather-GEMM with a zero row.

struct PrepD {
  long cpre, src, dst;
  int K, CI, CO, CB32, NT16, hf;
};

__global__ void k_sniff(const void* __restrict__ xraw, int* __restrict__ flagp) {
  __shared__ float smax[256];
  const u16* u = (const u16*)xraw;
  float m = 0.f;
  for (int i = threadIdx.x; i < 2048; i += 256) {
    float v = u2f(u[2 * i]);
    if (isnan(v) || isinf(v)) m = 1e30f; else m = fmaxf(m, fabsf(v));
  }
  smax[threadIdx.x] = m;
  __syncthreads();
  for (int s = 128; s > 0; s >>= 1) {
    if (threadIdx.x < s) smax[threadIdx.x] = fmaxf(smax[threadIdx.x], smax[threadIdx.x + s]);
    __syncthreads();
  }
  if (threadIdx.x == 0) *flagp = (smax[0] < 1e4f) ? 1 : 0;
}

__global__ __launch_bounds__(256) void k_prep_all(
    const void* __restrict__ P, const int* __restrict__ flagp, u16* __restrict__ W,
    const PrepD* __restrict__ T, int NL, long totalC, long totalE)
{
  int f = *flagp;
  int L = 0;
  for (long c = (long)blockIdx.x * 256 + threadIdx.x; c < totalC; c += (long)gridDim.x * 256) {
    while (L + 1 < NL && c >= T[L + 1].cpre) ++L;
    PrepD d = T[L];
    long lc = c - d.cpre;
    int lane = (int)(lc & 63); long t = lc >> 6;
    int nt = (int)(t % d.NT16); t /= d.NT16;
    int cb = (int)(t % d.CB32); int k = (int)(t / d.CB32);
    int co = nt * 16 + (lane & 15);
    int cib = cb * 32 + (lane >> 4) * 8;
    u16 hi[8], lo[8];
#pragma unroll
    for (int j = 0; j < 8; ++j) {
      int ci = cib + j; float v = 0.f;
      if (ci < d.CI && co < d.CO) v = pload(P, f, d.src + ((size_t)k * d.CI + ci) * d.CO + co);
      if (d.hf) { u16 h = f2h(v); hi[j] = h; lo[j] = f2h(v - h2f(h)); }
      else      { u16 h = f2u(v); hi[j] = h; lo[j] = f2u(v - u2f(h)); }
    }
    *(bfrag*)(W + d.dst + lc * 8) = *(const bfrag*)hi;
    *(bfrag*)(W + totalE + d.dst + lc * 8) = *(const bfrag*)lo;
  }
}

__global__ __launch_bounds__(256) void k_prep_frag(
    const void* __restrict__ P, const int* __restrict__ flagp, u16* __restrict__ W,
    long src, long halfel, int hf, int K, int CI, int CO, int CB32, int NT16)
{
  int f = *flagp;
  long total = (long)K * CB32 * NT16 * 64;
  for (long c = (long)blockIdx.x * 256 + threadIdx.x; c < total; c += (long)gridDim.x * 256) {
    int lane = (int)(c & 63); long t = c >> 6;
    int nt = (int)(t % NT16); t /= NT16;
    int cb = (int)(t % CB32); int k = (int)(t / CB32);
    int co = nt * 16 + (lane & 15);
    int cib = cb * 32 + (lane >> 4) * 8;
    u16 hi[8], lo[8];
#pragma unroll
    for (int j = 0; j < 8; ++j) {
      int ci = cib + j; float v = 0.f;
      if (ci < CI && co < CO) v = pload(P, f, src + ((size_t)k * CI + ci) * CO + co);
      if (hf) { u16 h = f2h(v); hi[j] = h; lo[j] = f2h(v - h2f(h)); }
      else    { u16 h = f2u(v); hi[j] = h; lo[j] = f2u(v - u2f(h)); }
    }
    *(bfrag*)(W + c * 8) = *(const bfrag*)hi;
    *(bfrag*)(W + halfel + c * 8) = *(const bfrag*)lo;
  }
}

__global__ void k_prep_bias(const void* __restrict__ P, const int* __restrict__ flagp,
                            float* __restrict__ B, long src, int n)
{
  int f = *flagp;
  int i = blockIdx.x * 256 + threadIdx.x;
  if (i < n) B[i] = pload(P, f, src + i);
}

// ---- pad input x [N,4] -> fp16 [N][32] ----
__global__ void k_pad(const void* __restrict__ xraw, const int* __restrict__ flagp,
                      u16* __restrict__ Xp, int N)
{
  int f = *flagp; int total = N * 32;
  for (int i = blockIdx.x * 256 + threadIdx.x; i < total; i += gridDim.x * 256) {
    int n = i >> 5, cc = i & 31;
    float v = (cc < 4) ? pload(xraw, f, (size_t)n * 4 + cc) : 0.f;
    Xp[i] = f2h(v);
  }
}

__global__ void k_mk_didx(const int* __restrict__ par, const int* __restrict__ off,
                          int* __restrict__ idx, int N, int ZR)
{
  int stride = gridDim.x * 256;
  for (int i = blockIdx.x * 256 + threadIdx.x; i < N; i += stride) {
    int p = par[i], o = off[i];
#pragma unroll
    for (int k = 0; k < 8; ++k) idx[(size_t)i * 8 + k] = (k == o) ? p : ZR;
  }
}

// ---- MFMA gather-GEMM, reduction-split over gridDim.z (fp16 A) ----
template<int NT>
__global__ __launch_bounds__(256) void k_conv_mfma(
    const void* __restrict__ Xv, const int* __restrict__ nbr,
    const u16* __restrict__ Wp, long halfel, float* __restrict__ Y,
    const float* __restrict__ bias, int relu, const int* __restrict__ flagp,
    int N, int K, int CB32, int NT16, int CO, int XS, int tlen, int atomic)
{
  const int f = *flagp;
  const int lane = threadIdx.x & 63;
  const int wv = threadIdx.x >> 6;
  const int rowbase = blockIdx.x * 128 + wv * 32;
  const int ntb = blockIdx.y * NT;
  const int ml = lane & 15;
  const int quad = lane >> 4;
  const int ktot = K * CB32;
  const int t0 = blockIdx.z * tlen;
  const int t1 = (t0 + tlen < ktot) ? (t0 + tlen) : ktot;
  if (t0 >= t1) return;

  f4 acc[2][NT];
#pragma unroll
  for (int i = 0; i < 2; ++i)
#pragma unroll
    for (int j = 0; j < NT; ++j) acc[i][j] = (f4)(0.f);

  int k = t0 / CB32;
  int cb = t0 - k * CB32;
  int idx[2];
  bool fresh = true;
  const u16* X = (const u16*)Xv;

  if (f) {
    // bf16 wire: weights exact in fp16 -> 1 MFMA per pair
    for (int t = t0; t < t1; ++t) {
      if (fresh) {
#pragma unroll
        for (int mt = 0; mt < 2; ++mt) {
          int r = rowbase + mt * 16 + ml;
          idx[mt] = (r < N) ? (nbr ? nbr[(size_t)r * K + k] : r) : 0;
        }
        fresh = false;
      }
      const u16* WH = Wp + (size_t)t * NT16 * 512;
      hfrag bh[NT];
#pragma unroll
      for (int nt = 0; nt < NT; ++nt)
        bh[nt] = *(const hfrag*)(WH + ((size_t)(ntb + nt) * 64 + lane) * 8);
      hfrag a[2];
#pragma unroll
      for (int mt = 0; mt < 2; ++mt)
        a[mt] = *(const hfrag*)(X + (size_t)idx[mt] * XS + cb * 32 + quad * 8);
#pragma unroll
      for (int mt = 0; mt < 2; ++mt)
#pragma unroll
        for (int nt = 0; nt < NT; ++nt)
          acc[mt][nt] = __builtin_amdgcn_mfma_f32_16x16x32_f16(a[mt], bh[nt], acc[mt][nt], 0, 0, 0);
      if (++cb == CB32) { cb = 0; ++k; fresh = true; }
    }
  } else {
    // fp32 wire: fp16 weight hi+lo passes
    for (int t = t0; t < t1; ++t) {
      if (fresh) {
#pragma unroll
        for (int mt = 0; mt < 2; ++mt) {
          int r = rowbase + mt * 16 + ml;
          idx[mt] = (r < N) ? (nbr ? nbr[(size_t)r * K + k] : r) : 0;
        }
        fresh = false;
      }
      const u16* WH = Wp + (size_t)t * NT16 * 512;
      const u16* WL = WH + halfel;
      hfrag bh[NT], bl[NT];
#pragma unroll
      for (int nt = 0; nt < NT; ++nt) {
        size_t o = ((size_t)(ntb + nt) * 64 + lane) * 8;
        bh[nt] = *(const hfrag*)(WH + o);
        bl[nt] = *(const hfrag*)(WL + o);
      }
      hfrag a[2];
#pragma unroll
      for (int mt = 0; mt < 2; ++mt)
        a[mt] = *(const hfrag*)(X + (size_t)idx[mt] * XS + cb * 32 + quad * 8);
#pragma unroll
      for (int mt = 0; mt < 2; ++mt)
#pragma unroll
        for (int nt = 0; nt < NT; ++nt) {
          acc[mt][nt] = __builtin_amdgcn_mfma_f32_16x16x32_f16(a[mt], bl[nt], acc[mt][nt], 0, 0, 0);
          acc[mt][nt] = __builtin_amdgcn_mfma_f32_16x16x32_f16(a[mt], bh[nt], acc[mt][nt], 0, 0, 0);
        }
      if (++cb == CB32) { cb = 0; ++k; fresh = true; }
    }
  }

#pragma unroll
  for (int mt = 0; mt < 2; ++mt) {
#pragma unroll
    for (int nt = 0; nt < NT; ++nt) {
      int col = (ntb + nt) * 16 + ml;
      if (col >= CO) continue;
      float bvv = bias ? bias[col] : 0.f;
#pragma unroll
      for (int reg = 0; reg < 4; ++reg) {
        int row = rowbase + mt * 16 + quad * 4 + reg;
        if (row < N) {
          if (atomic) {
            atomicAdd(&Y[(size_t)row * CO + col], acc[mt][nt][reg]);
          } else {
            float v = acc[mt][nt][reg] + bvv;
            if (relu) v = fmaxf(v, 0.f);
            Y[(size_t)row * CO + col] = v;
          }
        }
      }
    }
  }
}

__global__ void k_bias_relu(float* __restrict__ Y, const float* __restrict__ bias,
                            u16* __restrict__ d16, int relu, int total, int CO)
{
  int stride = gridDim.x * 256;
  for (int i = blockIdx.x * 256 + threadIdx.x; i < total; i += stride) {
    int c = i % CO;
    float v = Y[i] + (bias ? bias[c] : 0.f);
    if (relu) v = fmaxf(v, 0.f);
    Y[i] = v;
    if (d16) d16[i] = f2h(v);
  }
}

static void launch_conv(hipStream_t s, int bx, const void* X, const int* nbr,
                        const u16* W, long halfel, float* Y, const float* bias, int relu,
                        const int* flagp, int N, int K, int CB32, int NT16, int CO, int XS,
                        u16* d16)
{
  int NT = (NT16 % 6 == 0) ? 6 : ((NT16 % 4 == 0) ? 4 : 2);
  int ny = NT16 / NT;
  int ktot = K * CB32;
  long blocks = (long)bx * ny;
  int ZS = 1;
  if (ktot > 1) {
    ZS = (int)((1024 + blocks - 1) / blocks);
    if (ZS > ktot) ZS = ktot;
    if (ZS < 1) ZS = 1;
  }
  int tlen = cdiv(ktot, ZS);
  ZS = cdiv(ktot, tlen);
  int atomic = (ZS > 1) ? 1 : 0;
  if (atomic) hipMemsetAsync(Y, 0, (size_t)N * CO * 4, s);
  dim3 g(bx, ny, ZS);
  if (NT == 6)      k_conv_mfma<6><<<g, 256, 0, s>>>(X, nbr, W, halfel, Y, bias, relu, flagp, N, K, CB32, NT16, CO, XS, tlen, atomic);
  else if (NT == 4) k_conv_mfma<4><<<g, 256, 0, s>>>(X, nbr, W, halfel, Y, bias, relu, flagp, N, K, CB32, NT16, CO, XS, tlen, atomic);
  else              k_conv_mfma<2><<<g, 256, 0, s>>>(X, nbr, W, halfel, Y, bias, relu, flagp, N, K, CB32, NT16, CO, XS, tlen, atomic);
  if ((atomic && (bias || relu)) || d16) {
    int total = N * CO;
    int nb = cdiv(total, 1024); if (nb > 1024) nb = 1024; if (nb < 1) nb = 1;
    k_bias_relu<<<nb, 256, 0, s>>>(Y, atomic ? bias : nullptr, d16, atomic ? relu : 0, total, CO);
  }
}

__global__ __launch_bounds__(256) void k_bn_stats(
    const float* __restrict__ X, float* __restrict__ st, int total, int C)
{
  __shared__ float ssum[384], ssq[384];
  for (int c = threadIdx.x; c < C; c += 256) { ssum[c] = 0.f; ssq[c] = 0.f; }
  __syncthreads();
  int gid = blockIdx.x * 256 + threadIdx.x;
  int total4 = total >> 2;
  int stride = gridDim.x * 256;
  int c0 = (gid * 4) % C;
  float s0 = 0.f, s1 = 0.f, s2 = 0.f, s3 = 0.f;
  float q0 = 0.f, q1 = 0.f, q2 = 0.f, q3 = 0.f;
  for (int i = gid; i < total4; i += stride) {
    float4 v = ((const float4*)X)[i];
    s0 += v.x; q0 += v.x * v.x;
    s1 += v.y; q1 += v.y * v.y;
    s2 += v.z; q2 += v.z * v.z;
    s3 += v.w; q3 += v.w * v.w;
  }
  atomicAdd(&ssum[c0], s0);     atomicAdd(&ssq[c0], q0);
  atomicAdd(&ssum[c0 + 1], s1); atomicAdd(&ssq[c0 + 1], q1);
  atomicAdd(&ssum[c0 + 2], s2); atomicAdd(&ssq[c0 + 2], q2);
  atomicAdd(&ssum[c0 + 3], s3); atomicAdd(&ssq[c0 + 3], q3);
  __syncthreads();
  for (int c = threadIdx.x; c < C; c += 256) {
    atomicAdd(&st[c], ssum[c]); atomicAdd(&st[384 + c], ssq[c]);
  }
}

// ---- BN apply: fp32 in; add none / fp16; out fp16 ----
__global__ __launch_bounds__(256) void k_bn_apply(
    const float* __restrict__ X, const float* __restrict__ st,
    const u16* __restrict__ add2, u16* __restrict__ Y2,
    int relu, int total, int C, float invN)
{
  __shared__ float mean[384], rsig[384];
  for (int c = threadIdx.x; c < C; c += 256) {
    float mm = st[c] * invN;
    float vv = st[384 + c] * invN - mm * mm;
    mean[c] = mm; rsig[c] = rsqrtf(vv + 1e-5f);
  }
  __syncthreads();
  int gid = blockIdx.x * 256 + threadIdx.x;
  int total4 = total >> 2;
  int stride = gridDim.x * 256;
  int c0 = (gid * 4) % C;
  float m0 = mean[c0], m1 = mean[c0 + 1], m2 = mean[c0 + 2], m3 = mean[c0 + 3];
  float r0 = rsig[c0], r1 = rsig[c0 + 1], r2 = rsig[c0 + 2], r3 = rsig[c0 + 3];
  for (int i = gid; i < total4; i += stride) {
    float4 v = ((const float4*)X)[i];
    float w0 = (v.x - m0) * r0, w1 = (v.y - m1) * r1;
    float w2 = (v.z - m2) * r2, w3 = (v.w - m3) * r3;
    if (add2) {
      ushort4 ah = *(const ushort4*)(add2 + (size_t)i * 4);
      w0 += h2f(ah.x); w1 += h2f(ah.y); w2 += h2f(ah.z); w3 += h2f(ah.w);
    }
    if (relu) {
      w0 = fmaxf(w0, 0.f); w1 = fmaxf(w1, 0.f);
      w2 = fmaxf(w2, 0.f); w3 = fmaxf(w3, 0.f);
    }
    ushort4 hh; hh.x = f2h(w0); hh.y = f2h(w1); hh.z = f2h(w2); hh.w = f2h(w3);
    *(ushort4*)(Y2 + (size_t)i * 4) = hh;
  }
}

// ---- fp16 column copy (concat) ----
__global__ void k_copycols(const u16* __restrict__ S, u16* __restrict__ D,
                           int N, int Cs, int Cd, int off)
{
  int csq = Cs >> 2;
  int total4 = N * csq;
  int stride = gridDim.x * 256;
  for (int i = blockIdx.x * 256 + threadIdx.x; i < total4; i += stride) {
    int n = i / csq, cc = (i - n * csq) * 4;
    *(ushort4*)(D + (size_t)n * Cd + off + cc) = *(const ushort4*)(S + (size_t)i * 4);
  }
}

__global__ void k_store_dyn(const float* __restrict__ S, void* __restrict__ D,
                            const int* __restrict__ flagp, size_t eofs, int n)
{
  int f = *flagp;
  int n4 = n >> 2;
  int stride = gridDim.x * 256;
  for (int i = blockIdx.x * 256 + threadIdx.x; i < n4; i += stride) {
    float4 v = ((const float4*)S)[i];
    if (f) {
      ushort4 u;
      u.x = f2u(v.x); u.y = f2u(v.y); u.z = f2u(v.z); u.w = f2u(v.w);
      *(ushort4*)((u16*)D + eofs + (size_t)i * 4) = u;
    } else {
      *(float4*)((float*)D + eofs + (size_t)i * 4) = v;
    }
  }
}

static int build_table(PrepD* T, long* totalC, long* totalE) {
  int n = 0; long po = 0, ce = 0, cc = 0;
  auto W = [&](int K, int CI, int CO) {
    int CB = cdiv(CI, 32), NTx = cdiv(CO, 16);
    long ch = (long)K * CB * NTx * 64;
    T[n].cpre = cc; T[n].src = po; T[n].dst = ce;
    T[n].K = K; T[n].CI = CI; T[n].CO = CO; T[n].CB32 = CB; T[n].NT16 = NTx; T[n].hf = 1;
    ++n; cc += ch; ce += ch * 8; po += (long)K * CI * CO;
  };
  auto SKIP = [&](long e) { po += e; };
  W(27, 4, 32); W(27, 32, 32);
  W(8, 32, 32); W(27, 32, 32); W(27, 32, 32); W(27, 32, 32); W(27, 32, 32);
  W(8, 32, 32); W(27, 32, 64); W(27, 64, 64); W(1, 32, 64); W(27, 64, 64); W(27, 64, 64);
  W(8, 64, 64); W(27, 64, 128); W(27, 128, 128); W(1, 64, 128); W(27, 128, 128); W(27, 128, 128);
  W(8, 128, 128); W(27, 128, 256); W(27, 256, 256); W(1, 128, 256); W(27, 256, 256); W(27, 256, 256);
  W(8, 256, 256);   // up1 deconv
  W(27, 384, 256); W(27, 256, 256); W(1, 384, 256); W(27, 256, 256); W(27, 256, 256);
  W(8, 256, 128);   // up2 deconv
  W(27, 192, 128); W(27, 128, 128); W(1, 192, 128); W(27, 128, 128); W(27, 128, 128);
  W(8, 128, 96);    // up3 deconv
  W(27, 128, 96); W(27, 96, 96); W(1, 128, 96); W(27, 96, 96); W(27, 96, 96);
  W(8, 96, 96);     // up4 deconv
  W(27, 128, 96); W(27, 96, 96); W(1, 128, 96); W(27, 96, 96); W(27, 96, 96);
  W(1, 96, 19); SKIP(19); W(1, 96, 96); SKIP(96); W(1, 96, 128); SKIP(128);
  *totalC = cc; *totalE = ce;
  return n;
}

extern "C" void kernel_launch(void* const* d_in, const int* in_sizes, int n_in,
                              void* d_out, int out_size, void* d_ws, size_t ws_size,
                              hipStream_t stream)
{
  const void* xraw = d_in[0];
  const int* nbr0 = (const int*)d_in[1];
  const int* nbr1 = (const int*)d_in[2];
  const int* nbr2 = (const int*)d_in[3];
  const int* nbr3 = (const int*)d_in[4];
  const int* nbr4 = (const int*)d_in[5];
  const int* d1 = (const int*)d_in[6];
  const int* d2 = (const int*)d_in[7];
  const int* d3 = (const int*)d_in[8];
  const int* d4 = (const int*)d_in[9];
  const int* u1p = (const int*)d_in[10]; const int* u1o = (const int*)d_in[11];
  const int* u2p = (const int*)d_in[12]; const int* u2o = (const int*)d_in[13];
  const int* u3p = (const int*)d_in[14]; const int* u3o = (const int*)d_in[15];
  const int* u4p = (const int*)d_in[16]; const int* u4o = (const int*)d_in[17];
  const void* params = d_in[18];
  (void)in_sizes; (void)n_in;

  static PrepD h_table[64];
  long totalC = 0, totalE = 0;
  int NL = build_table(h_table, &totalC, &totalE);

  char* base = (char*)d_ws; size_t off = 0;
  auto ab = [&](size_t bytes) -> void* { void* p = base + off; off += (bytes + 63) & ~(size_t)63; return p; };
  int* flagp = (int*)ab(64);
  float* st = (float*)ab((size_t)64 * 768 * 4);
  float* Bstf = (float*)ab((size_t)512 * 4);
  int* didx = (int*)ab((size_t)NP0 * 8 * 4);
  // fp16 activation buffers (+1 zero row where a deconv reads them)
  u16* x0 = (u16*)ab((size_t)(NP0 + 1) * 32 * 2);
  u16* x1 = (u16*)ab((size_t)NP1 * 32 * 2);
  u16* x2 = (u16*)ab((size_t)NP2 * 64 * 2);
  u16* x3 = (u16*)ab((size_t)NP3 * 128 * 2);
  u16* x4 = (u16*)ab((size_t)(NP4 + 1) * 256 * 2);
  float* U  = (float*)ab((size_t)(NP0 + 1) * 96 * 4);   // fp32 conv scratch / fp16 (+zero row)
  float* A  = (float*)ab((size_t)NP0 * 96 * 4);
  float* B  = (float*)ab((size_t)NP0 * 128 * 4);
  u16* Xp = (u16*)B;   // overlay: Xp dead before B's first use

  size_t wall_bytes = (size_t)totalE * 4;
  size_t rem = (ws_size > off) ? (ws_size - off) : 0;
  bool bigprep = rem >= wall_bytes + 8192;
  u16* Wall = nullptr; PrepD* d_table = nullptr; u16* Wst = nullptr;
  if (bigprep) {
    Wall = (u16*)ab(wall_bytes);
    d_table = (PrepD*)ab(4096);
  } else {
    Wst = (u16*)ab((size_t)5400000 * 2);
  }
  if (off > ws_size) { hipMemsetAsync(d_out, 0, (size_t)out_size * 2, stream); return; }

  long po = 0;
  int bnc = 0;
  int wli = 0;

  auto prepF = [&](int K, int CI, int CO, int CB32, int NT16) -> long {
    long chunks = (long)K * CB32 * NT16 * 64;
    long halfel = chunks * 8;
    int nb = (int)((chunks + 255) / 256); if (nb > 4096) nb = 4096; if (nb < 1) nb = 1;
    k_prep_frag<<<nb, 256, 0, stream>>>(params, flagp, Wst, po, halfel, 1, K, CI, CO, CB32, NT16);
    po += (long)K * CI * CO;
    return halfel;
  };
  auto getW = [&](int K, int CI, int CO, int CB32, int NT16, const u16** Wp, long* he) {
    if (bigprep) {
      *Wp = Wall + h_table[wli].dst; *he = totalE;
      ++wli; po += (long)K * CI * CO;
    } else {
      *he = prepF(K, CI, CO, CB32, NT16); *Wp = Wst;
    }
  };
  auto convop = [&](const u16* X, const int* nb_, int K, int CI, int CO, float* Y, int N, int XS) {
    int CB32 = cdiv(CI, 32), NT16 = cdiv(CO, 16);
    const u16* Wp; long he;
    getW(K, CI, CO, CB32, NT16, &Wp, &he);
    launch_conv(stream, cdiv(N, 128), X, nb_, Wp, he, Y, nullptr, 0, flagp, N, K, CB32, NT16, CO, XS, nullptr);
  };
  auto linop = [&](const u16* X, int CI, int CO, float* Y, int N, bool bias, int relu, u16* d16) {
    int CB32 = cdiv(CI, 32), NT16 = cdiv(CO, 16);
    const u16* Wp; long he;
    getW(1, CI, CO, CB32, NT16, &Wp, &he);
    const float* bp = nullptr;
    if (bias) {
      k_prep_bias<<<cdiv(CO, 256), 256, 0, stream>>>(params, flagp, Bstf, po, CO);
      po += CO; bp = Bstf;
    }
    launch_conv(stream, cdiv(N, 128), X, nullptr, Wp, he, Y, bp, relu, flagp, N, 1, CB32, NT16, CO, CI, d16);
  };
  // deconv as masked K=8 gather-GEMM; X has a zero row at index Ns
  auto deconvop = [&](const u16* X, int Ns, const int* par, const int* ofv,
                      int CI, int CO, float* Y, int N) {
    hipMemsetAsync((void*)(X + (size_t)Ns * CI), 0, (size_t)CI * 2, stream);
    int nbl = cdiv(N, 256); if (nbl > 1024) nbl = 1024; if (nbl < 1) nbl = 1;
    k_mk_didx<<<nbl, 256, 0, stream>>>(par, ofv, didx, N, Ns);
    convop(X, didx, 8, CI, CO, Y, N, CI);
  };
  auto bnop = [&](const float* X, int N, int C, const u16* add2, int relu, u16* out2) {
    float* slot = st + (size_t)(bnc++) * 768;
    int total = N * C;
    int total4 = total >> 2;
    int nb1 = cdiv(total4, 4096); if (nb1 > 504) nb1 = 504; if (nb1 < 3) nb1 = 3;
    nb1 = ((nb1 + 2) / 3) * 3;
    k_bn_stats<<<nb1, 256, 0, stream>>>(X, slot, total, C);
    int nb2 = cdiv(total4, 2048); if (nb2 > 510) nb2 = 510; if (nb2 < 3) nb2 = 3;
    nb2 = ((nb2 + 2) / 3) * 3;
    k_bn_apply<<<nb2, 256, 0, stream>>>(X, slot, add2, out2, relu, total, C, 1.0f / (float)N);
  };
  auto copyop = [&](const u16* S, u16* D, int N, int Cs, int Cd, int o2) {
    int total4 = (N * Cs) >> 2;
    int nb3 = cdiv(total4, 1024); if (nb3 > 1024) nb3 = 1024; if (nb3 < 1) nb3 = 1;
    k_copycols<<<nb3, 256, 0, stream>>>(S, D, N, Cs, Cd, o2);
  };
  auto storeop = [&](const float* S, size_t eo, int n) {
    int nb4 = cdiv(n >> 2, 1024); if (nb4 > 1024) nb4 = 1024; if (nb4 < 1) nb4 = 1;
    k_store_dyn<<<nb4, 256, 0, stream>>>(S, d_out, flagp, eo, n);
  };
  // fp16 resblock: conv(H16->t1 f32); bn(t1->t2 f16); conv(t2->t1 f32);
  // CI==CO: bn(t1, add=H16 -> OUT16)
  // else:   linop(H16->t2 f32, H dead); bn(t2->OUT16); bn(t1, add=OUT16 -> OUT16)
  auto resblock16 = [&](const int* nb, int N, int CI, int CO,
                        u16* H16, float* t1, float* t2, u16* OUT16) {
    convop(H16, nb, 27, CI, CO, t1, N, CI);
    bnop(t1, N, CO, nullptr, 1, (u16*)t2);
    convop((u16*)t2, nb, 27, CO, CO, t1, N, CO);
    if (CI == CO) {
      bnop(t1, N, CO, H16, 1, OUT16);
    } else {
      linop(H16, CI, CO, t2, N, false, 0, nullptr);
      bnop(t2, N, CO, nullptr, 0, OUT16);
      bnop(t1, N, CO, OUT16, 1, OUT16);   // element-aligned alias: safe
    }
  };

  k_sniff<<<1, 256, 0, stream>>>(xraw, flagp);
  if (bigprep) {
    hipMemcpyAsync(d_table, h_table, (size_t)NL * sizeof(PrepD), hipMemcpyHostToDevice, stream);
    int nbp = (int)((totalC + 255) / 256); if (nbp > 4096) nbp = 4096;
    k_prep_all<<<nbp, 256, 0, stream>>>(params, flagp, Wall, d_table, NL, totalC, totalE);
  }
  hipMemsetAsync(st, 0, (size_t)64 * 768 * 4, stream);
  k_pad<<<1024, 256, 0, stream>>>(xraw, flagp, Xp, NP0);

  u16* U16 = (u16*)U; u16* B16 = (u16*)B; u16* A16 = (u16*)A;

  // stem: Xp(=B16 overlay) -> A(f32) -> U16 -> A(f32) -> x0
  convop(Xp, nbr0, 27, 4, 32, A, NP0, 32);
  bnop(A, NP0, 32, nullptr, 1, U16);
  convop(U16, nbr0, 27, 32, 32, A, NP0, 32);
  bnop(A, NP0, 32, nullptr, 1, x0);
  // stage1
  convop(x0, d1, 8, 32, 32, A, NP1, 32); bnop(A, NP1, 32, nullptr, 1, U16);
  resblock16(nbr1, NP1, 32, 32, U16, A, B, U16);
  resblock16(nbr1, NP1, 32, 32, U16, A, B, x1);
  // stage2
  convop(x1, d2, 8, 32, 32, A, NP2, 32); bnop(A, NP2, 32, nullptr, 1, U16);
  resblock16(nbr2, NP2, 32, 64, U16, A, B, U16);
  resblock16(nbr2, NP2, 64, 64, U16, A, B, x2);
  // stage3
  convop(x2, d3, 8, 64, 64, A, NP3, 64); bnop(A, NP3, 64, nullptr, 1, U16);
  resblock16(nbr3, NP3, 64, 128, U16, A, B, U16);
  resblock16(nbr3, NP3, 128, 128, U16, A, B, x3);
  // stage4
  convop(x3, d4, 8, 128, 128, A, NP4, 128); bnop(A, NP4, 128, nullptr, 1, U16);
  resblock16(nbr4, NP4, 128, 256, U16, A, B, U16);
  resblock16(nbr4, NP4, 256, 256, U16, A, B, x4);
  // up1
  deconvop(x4, NP4, u1p, u1o, 256, 256, A, NP3);
  bnop(A, NP3, 256, nullptr, 1, U16);
  copyop(U16, B16, NP3, 256, 384, 0); copyop(x3, B16, NP3, 128, 384, 256);
  resblock16(nbr3, NP3, 384, 256, B16, A, U, B16);
  resblock16(nbr3, NP3, 256, 256, B16, A, U, U16);
  // up2
  deconvop(U16, NP3, u2p, u2o, 256, 128, A, NP2);
  bnop(A, NP2, 128, nullptr, 1, U16);
  copyop(U16, B16, NP2, 128, 192, 0); copyop(x2, B16, NP2, 64, 192, 128);
  resblock16(nbr2, NP2, 192, 128, B16, A, U, B16);
  resblock16(nbr2, NP2, 128, 128, B16, A, U, U16);
  // up3
  deconvop(U16, NP2, u3p, u3o, 128, 96, A, NP1);
  bnop(A, NP1, 96, nullptr, 1, U16);
  copyop(U16, B16, NP1, 96, 128, 0); copyop(x1, B16, NP1, 32, 128, 96);
  resblock16(nbr1, NP1, 128, 96, B16, A, U, B16);
  resblock16(nbr1, NP1, 96, 96, B16, A, U, U16);
  // up4
  deconvop(U16, NP1, u4p, u4o, 96, 96, A, NP0);
  bnop(A, NP0, 96, nullptr, 1, U16);
  copyop(U16, B16, NP0, 96, 128, 0); copyop(x0, B16, NP0, 32, 128, 96);
  resblock16(nbr0, NP0, 128, 96, B16, A, U, B16);
  resblock16(nbr0, NP0, 96, 96, B16, A, U, U16);
  // head: logits -> x0 region (fp32 view, x0 dead); hidden fp16 -> A16; feat -> B
  float* x0f = (float*)x0;
  linop(U16, 96, 19, x0f, NP0, true, 0, nullptr);
  linop(U16, 96, 96, B, NP0, true, 1, A16);
  linop(A16, 96, 128, B, NP0, true, 0, nullptr);
  storeop(x0f, 0, NP0 * 19);
  storeop(B, (size_t)NP0 * 19, NP0 * 128);
}